// Round 4
// baseline (1247.508 us; speedup 1.0000x reference)
//
#include <hip/hip_runtime.h>
#include <math.h>

#define NN 100000
#define NE 1600000
#define NEG_SLOPE 0.2f

typedef __attribute__((ext_vector_type(8))) short bf16x8;
typedef __attribute__((ext_vector_type(4))) float f32x4;
typedef __attribute__((ext_vector_type(2))) float f32x2;

__device__ __forceinline__ float b2f(unsigned short u) {
  union { unsigned u; float f; } c; c.u = ((unsigned)u) << 16; return c.f;
}
__device__ __forceinline__ unsigned short f2b(float x) {
  union { float f; unsigned u; } c; c.f = x;
  unsigned r = c.u + 0x7FFFu + ((c.u >> 16) & 1u);
  return (unsigned short)(r >> 16);
}
__device__ __forceinline__ void fma4(float4& acc, float s, const float4& b) {
  acc.x = fmaf(s, b.x, acc.x);
  acc.y = fmaf(s, b.y, acc.y);
  acc.z = fmaf(s, b.z, acc.z);
  acc.w = fmaf(s, b.w, acc.w);
}

// ---------------- utility ----------------
__global__ __launch_bounds__(256) void k_zero(int* __restrict__ p, int nwords) {
  int i = blockIdx.x * 256 + threadIdx.x;
  if (i < nwords) p[i] = 0;
}

// zero the dummy rows (index NN) of the bf16 buffers
__global__ void k_zrow(unsigned short* __restrict__ a, unsigned short* __restrict__ b,
                       unsigned short* __restrict__ c) {
  int i = threadIdx.x;
  a[(size_t)NN * 64 + i] = 0;
  b[(size_t)NN * 64 + i] = 0;
  c[(size_t)NN * 64 + i] = 0;
}

__global__ __launch_bounds__(256) void k_cast(const float* __restrict__ A, unsigned short* __restrict__ Ab) {
  int i = blockIdx.x * 256 + threadIdx.x;
  int i4 = i * 4;
  if (i4 < NN * 128) {
    float4 v = *(const float4*)&A[i4];
    ushort4 o; o.x = f2b(v.x); o.y = f2b(v.y); o.z = f2b(v.z); o.w = f2b(v.w);
    *(ushort4*)&Ab[i4] = o;
  }
}

// ---------------- CSR build (unordered within row) ----------------
__global__ __launch_bounds__(256) void k_deg(const int* __restrict__ dst, int* __restrict__ deg) {
  int i = blockIdx.x * 256 + threadIdx.x;
  if (i < NE) atomicAdd(&deg[dst[i]], 1);
}

__global__ __launch_bounds__(256) void k_alloc(const int* __restrict__ deg, int* __restrict__ row_start,
                                               int* __restrict__ counter, float* __restrict__ nrm,
                                               int* __restrict__ dcount) {
  int i = blockIdx.x * 256 + threadIdx.x;
  if (i < NN) {
    int d = deg[i];
    row_start[i] = atomicAdd(counter, d);
    nrm[i] = rsqrtf(fmaxf((float)d, 1.0f));
    atomicAdd(&dcount[d < 63 ? d : 63], 1);
  }
}

__global__ void k_dbase(const int* __restrict__ dcount, int* __restrict__ dbase) {
  if (threadIdx.x == 0) {
    int s = 0;
    for (int b = 0; b < 64; ++b) { dbase[b] = s; s += dcount[b]; }
  }
}

__global__ __launch_bounds__(256) void k_dperm(const int* __restrict__ deg, const int* __restrict__ dbase,
                                               int* __restrict__ dcur, int* __restrict__ perm) {
  int i = blockIdx.x * 256 + threadIdx.x;
  if (i < NN) {
    int b = deg[i] < 63 ? deg[i] : 63;
    int p = dbase[b] + atomicAdd(&dcur[b], 1);
    perm[p] = i;
  }
}

__global__ __launch_bounds__(256) void k_scatter(const int* __restrict__ src, const int* __restrict__ dst,
                                                 const int* __restrict__ row_start, int* __restrict__ cursor,
                                                 int* __restrict__ csr_src) {
  int i = blockIdx.x * 256 + threadIdx.x;
  if (i < NE) {
    int n = dst[i];
    int p = atomicAdd(&cursor[n], 1);
    csr_src[row_start[n] + p] = src[i];
  }
}

// ---------------- fold attention vectors into W_fc: w[p][k], p = side*4+h ----------------
__global__ __launch_bounds__(256) void k_prepw(const float* __restrict__ W_fc, const float* __restrict__ al,
                                               const float* __restrict__ ar, float* __restrict__ w) {
  int o = blockIdx.x * 256 + threadIdx.x;  // [0,1024)
  if (o >= 1024) return;
  int side = o >> 9;
  int h = (o >> 7) & 3;
  int k = o & 127;
  const float* a = side ? ar : al;
  float s = 0.f;
  for (int d = 0; d < 64; ++d) s += W_fc[k * 256 + h * 64 + d] * a[h * 64 + d];
  w[(side * 4 + h) * 128 + k] = s;
}

// ---------------- exact el/er GEMV from bf16 features: thread = (node, p) ----------------
__global__ __launch_bounds__(256) void k_elr2(const unsigned short* __restrict__ X, const float* __restrict__ w,
                                              float* __restrict__ el, float* __restrict__ er) {
  int n = blockIdx.x * 32 + (threadIdx.x >> 3);
  int p = threadIdx.x & 7;
  if (n >= NN) return;
  const uint4* xr = (const uint4*)(X + (size_t)n * 128);
  const float4* wr = (const float4*)(w + p * 128);
  float s = 0.f;
#pragma unroll
  for (int i = 0; i < 16; ++i) {
    uint4 x = xr[i];
    float4 w0 = wr[2 * i], w1 = wr[2 * i + 1];
    s += __uint_as_float(x.x << 16) * w0.x + __uint_as_float(x.x & 0xFFFF0000u) * w0.y
       + __uint_as_float(x.y << 16) * w0.z + __uint_as_float(x.y & 0xFFFF0000u) * w0.w
       + __uint_as_float(x.z << 16) * w1.x + __uint_as_float(x.z & 0xFFFF0000u) * w1.y
       + __uint_as_float(x.w << 16) * w1.z + __uint_as_float(x.w & 0xFFFF0000u) * w1.w;
  }
  if (p < 4) el[n * 4 + p] = s;
  else er[n * 4 + (p - 4)] = s;
}

// ---------------- pre-pack B (both weight mats) into MFMA fragment order ----------------
// layout: [y][kt][nt][quad*16+nn][j]  (kt outer so each kt-pair half is contiguous 16 KB)
__global__ __launch_bounds__(256) void k_prepB(const float* __restrict__ W_fc, const float* __restrict__ W_rg,
                                               unsigned short* __restrict__ Bp) {
  int y = blockIdx.y;
  const float* Bsrc = (y >> 1) ? W_rg : W_fc;
  int colbase = (y & 1) * 128;
  for (int e = blockIdx.x * 256 + threadIdx.x; e < 16384; e += 2048) {
    int n = e & 127, k = e >> 7;
    int p = colbase + n;
    int d = p >> 2, hh = p & 3;
    float v = Bsrc[k * 256 + hh * 64 + d];
    int nt = n >> 4, nn = n & 15, kt = k >> 5, quad = (k >> 3) & 3, j = k & 7;
    Bp[(size_t)y * 16384 + ((kt * 8 + nt) * 64 + quad * 16 + nn) * 8 + j] = f2b(v);
  }
}

// ---------------- merged bf16 MFMA GEMM (LDS-staged A, coalesced epilogue) ----------------
// y=0,1 -> feat8 (fp8, (n,d,h) interleaved); y=2,3 -> resval2 (bf16 interleaved)
__global__ __launch_bounds__(256) void k_gemm_mfma(const unsigned short* __restrict__ Abf,
                                                   const unsigned short* __restrict__ Bp,
                                                   unsigned* __restrict__ feat8u,
                                                   unsigned short* __restrict__ resval2) {
  __shared__ unsigned short Al[128 * 136];  // A tile, 272-B row stride (pad kills bank conflicts)
  __shared__ unsigned short Bl[8192];       // B kt-pair half (16 KB)
  int tid = threadIdx.x;
  int half = blockIdx.y >> 1;
  int colbase = (blockIdx.y & 1) * 128;
  int row0 = blockIdx.x * 128;
  // stage A: 2048 chunks of 16 B, fully coalesced
#pragma unroll
  for (int i = 0; i < 8; ++i) {
    int c = tid + i * 256;
    int row = c >> 4, part = c & 15;
    int gr = row0 + row; if (gr > NN - 1) gr = NN - 1;
    *(uint4*)&Al[row * 136 + part * 8] = *(const uint4*)&Abf[(size_t)gr * 128 + part * 8];
  }
  // stage B half 0 (kt = 0,1)
  {
    const uint4* srcb = (const uint4*)(Bp + (size_t)blockIdx.y * 16384);
    uint4* dst4 = (uint4*)Bl;
#pragma unroll
    for (int i = 0; i < 4; ++i) dst4[tid + i * 256] = srcb[tid + i * 256];
  }
  __syncthreads();
  int w = tid >> 6, lane = tid & 63;
  int quad = lane >> 4, l16 = lane & 15;
  f32x4 acc[8][2];
#pragma unroll
  for (int rt = 0; rt < 8; ++rt)
#pragma unroll
    for (int c = 0; c < 2; ++c) acc[rt][c] = (f32x4){0.f, 0.f, 0.f, 0.f};
#pragma unroll
  for (int kh = 0; kh < 2; ++kh) {
    if (kh == 1) {
      __syncthreads();  // everyone done reading B half 0
      const uint4* srcb = (const uint4*)(Bp + (size_t)blockIdx.y * 16384 + 8192);
      uint4* dst4 = (uint4*)Bl;
#pragma unroll
      for (int i = 0; i < 4; ++i) dst4[tid + i * 256] = srcb[tid + i * 256];
      __syncthreads();
    }
#pragma unroll
    for (int ktl = 0; ktl < 2; ++ktl) {
      int kt = kh * 2 + ktl;
      bf16x8 b0 = *(const bf16x8*)&Bl[((ktl * 8 + w * 2 + 0) * 64 + lane) * 8];
      bf16x8 b1 = *(const bf16x8*)&Bl[((ktl * 8 + w * 2 + 1) * 64 + lane) * 8];
      int kb = kt * 32 + quad * 8;
#pragma unroll
      for (int rt = 0; rt < 8; ++rt) {
        bf16x8 a = *(const bf16x8*)&Al[(rt * 16 + l16) * 136 + kb];
        acc[rt][0] = __builtin_amdgcn_mfma_f32_16x16x32_bf16(b0, a, acc[rt][0], 0, 0, 0);
        acc[rt][1] = __builtin_amdgcn_mfma_f32_16x16x32_bf16(b1, a, acc[rt][1], 0, 0, 0);
      }
    }
  }
  __syncthreads();  // Al/Bl reads done; reuse Al for epilogue staging
  if (half == 0) {
    unsigned* Cl = (unsigned*)Al;  // [128][36] dwords (pad 32->36)
#pragma unroll
    for (int rt = 0; rt < 8; ++rt)
#pragma unroll
      for (int c = 0; c < 2; ++c) {
        int pk = __builtin_amdgcn_cvt_pk_fp8_f32(acc[rt][c][0], acc[rt][c][1], 0, false);
        pk = __builtin_amdgcn_cvt_pk_fp8_f32(acc[rt][c][2], acc[rt][c][3], pk, true);
        Cl[(rt * 16 + l16) * 36 + (w * 2 + c) * 4 + quad] = (unsigned)pk;
      }
    __syncthreads();
#pragma unroll
    for (int i = 0; i < 4; ++i) {
      int c = tid + i * 256;        // 1024 chunks: 128 rows x 8 uint4
      int row = c >> 3, wp = c & 7;
      int m = row0 + row;
      if (m < NN)
        *(uint4*)&feat8u[(size_t)m * 64 + (colbase >> 2) + wp * 4] = *(const uint4*)&Cl[row * 36 + wp * 4];
    }
  } else {
#pragma unroll
    for (int rt = 0; rt < 8; ++rt)
#pragma unroll
      for (int c = 0; c < 2; ++c) {
        int col = (w * 2 + c) * 16 + quad * 4;
        ushort4 o;
        o.x = f2b(acc[rt][c][0]); o.y = f2b(acc[rt][c][1]);
        o.z = f2b(acc[rt][c][2]); o.w = f2b(acc[rt][c][3]);
        *(ushort4*)&Al[(rt * 16 + l16) * 136 + col] = o;
      }
    __syncthreads();
#pragma unroll
    for (int i = 0; i < 8; ++i) {
      int c = tid + i * 256;        // 2048 chunks: 128 rows x 16 uint4
      int row = c >> 4, part = c & 15;
      int m = row0 + row;
      if (m < NN)
        *(uint4*)&resval2[(size_t)m * 256 + colbase + part * 8] = *(const uint4*)&Al[row * 136 + part * 8];
    }
  }
}

// ---------------- res2_f32[N x 64] = relu(A[N x 128] * W_res^T + b_res) (fp32 VALU) ----------------
__global__ __launch_bounds__(256) void k_gemm_nt_bias_relu(const float* __restrict__ A, const float* __restrict__ B,
                                                           const float* __restrict__ bias, float* __restrict__ C) {
  __shared__ float Bl[128][68];
  for (int idx = threadIdx.x; idx < 64 * 128; idx += 256) {
    int d = idx >> 7, k = idx & 127;
    Bl[k][d] = B[d * 128 + k];
  }
  __syncthreads();
  int tx = threadIdx.x & 15, ty = threadIdx.x >> 4;
  int row0 = blockIdx.x * 64 + ty * 4;
  const float* ap[4];
#pragma unroll
  for (int r = 0; r < 4; ++r) ap[r] = A + (size_t)min(row0 + r, NN - 1) * 128;
  float4 acc[4];
#pragma unroll
  for (int r = 0; r < 4; ++r) acc[r] = make_float4(0.f, 0.f, 0.f, 0.f);
#pragma unroll 2
  for (int k0 = 0; k0 < 128; k0 += 4) {
    float4 b0 = *(const float4*)&Bl[k0][tx * 4];
    float4 b1 = *(const float4*)&Bl[k0 + 1][tx * 4];
    float4 b2 = *(const float4*)&Bl[k0 + 2][tx * 4];
    float4 b3 = *(const float4*)&Bl[k0 + 3][tx * 4];
#pragma unroll
    for (int r = 0; r < 4; ++r) {
      float4 a = *(const float4*)(ap[r] + k0);
      fma4(acc[r], a.x, b0); fma4(acc[r], a.y, b1);
      fma4(acc[r], a.z, b2); fma4(acc[r], a.w, b3);
    }
  }
  float4 bv = *(const float4*)&bias[tx * 4];
#pragma unroll
  for (int r = 0; r < 4; ++r) {
    int row = row0 + r;
    if (row < NN) {
      float4 v;
      v.x = fmaxf(acc[r].x + bv.x, 0.f);
      v.y = fmaxf(acc[r].y + bv.y, 0.f);
      v.z = fmaxf(acc[r].z + bv.z, 0.f);
      v.w = fmaxf(acc[r].w + bv.w, 0.f);
      *(float4*)&C[(size_t)row * 64 + tx * 4] = v;
    }
  }
}

// ---------------- fused edge-softmax + aggregation + relu + head-mix conv ----------------
// 4 nodes per wave (degree-sorted via perm), 16 lanes per node, lane k owns dims 4k..4k+3.
// No cross-lane reduction for accumulators; only den needs a 16-wide reduce.
__global__ __launch_bounds__(256) void k_gat(const int* __restrict__ perm, const int* __restrict__ row_start,
                                             const int* __restrict__ deg, const int* __restrict__ csr_src,
                                             const float* __restrict__ el, const float* __restrict__ er,
                                             const unsigned* __restrict__ feat8u,
                                             const unsigned short* __restrict__ resval2,
                                             const float* __restrict__ gat_bias, const float* __restrict__ conv_w,
                                             const float* __restrict__ conv_b, const float* __restrict__ nrm,
                                             float* __restrict__ h0, unsigned short* __restrict__ hs0o) {
  __shared__ int s_src[4][4][16];
  __shared__ float s_x[4][4][16][4];
  int wid = threadIdx.x >> 6, lane = threadIdx.x & 63;
  int g = lane >> 4, k = lane & 15;
  int n = perm[blockIdx.x * 16 + wid * 4 + g];   // grid*16 == NN exactly
  int s0 = row_start[n], cnt = deg[n];
  float4 er4 = *(const float4*)&er[n * 4];
  unsigned koff = (unsigned)(k << 4);
  f32x2 a01[4], a23[4];
#pragma unroll
  for (int i = 0; i < 4; ++i) { a01[i] = (f32x2){0.f, 0.f}; a23[i] = (f32x2){0.f, 0.f}; }
  f32x2 den01 = (f32x2){0.f, 0.f}, den23 = (f32x2){0.f, 0.f};
  int cm = cnt;
  cm = max(cm, __shfl_xor(cm, 16, 64));
  cm = max(cm, __shfl_xor(cm, 32, 64));
  for (int base = 0; base < cm; base += 16) {
    int j = base + k;
    int s = 0;
    float x0 = 0.f, x1 = 0.f, x2 = 0.f, x3 = 0.f;
    if (j < cnt) {
      s = csr_src[s0 + j];
      float4 el4 = *(const float4*)&el[s * 4];
      float e0 = el4.x + er4.x; e0 = (e0 > 0.f) ? e0 : NEG_SLOPE * e0;
      float e1 = el4.y + er4.y; e1 = (e1 > 0.f) ? e1 : NEG_SLOPE * e1;
      float e2 = el4.z + er4.z; e2 = (e2 > 0.f) ? e2 : NEG_SLOPE * e2;
      float e3 = el4.w + er4.w; e3 = (e3 > 0.f) ? e3 : NEG_SLOPE * e3;
      x0 = __expf(e0); x1 = __expf(e1); x2 = __expf(e2); x3 = __expf(e3);
    }
    s_src[wid][g][k] = s;
    *(float4*)&s_x[wid][g][k][0] = make_float4(x0, x1, x2, x3);
    den01 += (f32x2){x0, x1}; den23 += (f32x2){x2, x3};
    int tm = cm - base; if (tm > 16) tm = 16;
    for (int t = 0; t < tm; ++t) {
      int s_ = s_src[wid][g][t];
      float4 x4 = *(const float4*)&s_x[wid][g][t][0];
      uint4 f = *(const uint4*)((const char*)feat8u + (((unsigned)s_ << 8) + koff));
      f32x2 x01 = (f32x2){x4.x, x4.y}, x23 = (f32x2){x4.z, x4.w};
      f32x2 lo, hi;
      lo = __builtin_amdgcn_cvt_pk_f32_fp8((int)f.x, false);
      hi = __builtin_amdgcn_cvt_pk_f32_fp8((int)f.x, true);
      a01[0] += x01 * lo; a23[0] += x23 * hi;
      lo = __builtin_amdgcn_cvt_pk_f32_fp8((int)f.y, false);
      hi = __builtin_amdgcn_cvt_pk_f32_fp8((int)f.y, true);
      a01[1] += x01 * lo; a23[1] += x23 * hi;
      lo = __builtin_amdgcn_cvt_pk_f32_fp8((int)f.z, false);
      hi = __builtin_amdgcn_cvt_pk_f32_fp8((int)f.z, true);
      a01[2] += x01 * lo; a23[2] += x23 * hi;
      lo = __builtin_amdgcn_cvt_pk_f32_fp8((int)f.w, false);
      hi = __builtin_amdgcn_cvt_pk_f32_fp8((int)f.w, true);
      a01[3] += x01 * lo; a23[3] += x23 * hi;
    }
  }
  // den reduce within each 16-lane group
#pragma unroll
  for (int off = 1; off < 16; off <<= 1) {
    den01[0] += __shfl_xor(den01[0], off, 64);
    den01[1] += __shfl_xor(den01[1], off, 64);
    den23[0] += __shfl_xor(den23[0], off, 64);
    den23[1] += __shfl_xor(den23[1], off, 64);
  }
  float i0 = 1.f / fmaxf(den01[0], 1e-9f);
  float i1 = 1.f / fmaxf(den01[1], 1e-9f);
  float i2 = 1.f / fmaxf(den23[0], 1e-9f);
  float i3 = 1.f / fmaxf(den23[1], 1e-9f);
  // epilogue: lane k handles dims 4k..4k+3 of node n
  uint4 rv0 = *(const uint4*)&resval2[(size_t)n * 256 + (k << 4)];
  uint4 rv1 = *(const uint4*)&resval2[(size_t)n * 256 + (k << 4) + 8];
  unsigned short c[16];
  *(uint4*)&c[0] = rv0; *(uint4*)&c[8] = rv1;
  int d0 = k << 2;
  float4 b0 = *(const float4*)&gat_bias[d0];
  float4 b1 = *(const float4*)&gat_bias[64 + d0];
  float4 b2 = *(const float4*)&gat_bias[128 + d0];
  float4 b3 = *(const float4*)&gat_bias[192 + d0];
  float bh0[4] = {b0.x, b0.y, b0.z, b0.w};
  float bh1[4] = {b1.x, b1.y, b1.z, b1.w};
  float bh2[4] = {b2.x, b2.y, b2.z, b2.w};
  float bh3[4] = {b3.x, b3.y, b3.z, b3.w};
  float cb = conv_b[0];
  float cw0 = conv_w[0], cw1 = conv_w[1], cw2 = conv_w[2], cw3 = conv_w[3];
  float hm[4];
#pragma unroll
  for (int i = 0; i < 4; ++i) {
    float t_, hmv = cb;
    t_ = fmaf(a01[i][0], i0, b2f(c[4 * i + 0]) + bh0[i]); t_ = fmaxf(t_, 0.f); hmv = fmaf(cw0, t_, hmv);
    t_ = fmaf(a01[i][1], i1, b2f(c[4 * i + 1]) + bh1[i]); t_ = fmaxf(t_, 0.f); hmv = fmaf(cw1, t_, hmv);
    t_ = fmaf(a23[i][0], i2, b2f(c[4 * i + 2]) + bh2[i]); t_ = fmaxf(t_, 0.f); hmv = fmaf(cw2, t_, hmv);
    t_ = fmaf(a23[i][1], i3, b2f(c[4 * i + 3]) + bh3[i]); t_ = fmaxf(t_, 0.f); hmv = fmaf(cw3, t_, hmv);
    hm[i] = hmv;
  }
  float nn_ = nrm[n];
  size_t o = (size_t)n * 64 + d0;
  *(float4*)&h0[o] = make_float4(hm[0], hm[1], hm[2], hm[3]);
  ushort4 hs;
  hs.x = f2b(hm[0] * nn_); hs.y = f2b(hm[1] * nn_);
  hs.z = f2b(hm[2] * nn_); hs.w = f2b(hm[3] * nn_);
  *(ushort4*)&hs0o[o] = hs;
}

// ---------------- APPNP gather core: 4 nodes/wave, 16 lanes/node, lane owns dims 4k..4k+3 ----------------
__device__ __forceinline__ void gather4(const int* __restrict__ perm, const int* __restrict__ row_start,
                                        const int* __restrict__ deg, const int* __restrict__ csr_src,
                                        const unsigned short* __restrict__ hs_in,
                                        int wid, int lane, int& n, int& k, float (&a)[4]) {
  __shared__ int s_src[4][4][16];
  int g = lane >> 4; k = lane & 15;
  n = perm[blockIdx.x * 16 + wid * 4 + g];
  int s0 = row_start[n], cnt = deg[n];
  unsigned koff = (unsigned)(k << 3);
  a[0] = 0.f; a[1] = 0.f; a[2] = 0.f; a[3] = 0.f;
  int cm = cnt;
  cm = max(cm, __shfl_xor(cm, 16, 64));
  cm = max(cm, __shfl_xor(cm, 32, 64));
  for (int base = 0; base < cm; base += 16) {
    int j = base + k;
    s_src[wid][g][k] = (j < cnt) ? csr_src[s0 + j] : NN;  // row NN is zeroed
    int tm = cm - base; if (tm > 16) tm = 16;
    for (int t = 0; t < tm; ++t) {
      int s = s_src[wid][g][t];
      uint2 u = *(const uint2*)((const char*)hs_in + (((unsigned)s << 7) + koff));
      a[0] += __uint_as_float(u.x << 16);
      a[1] += __uint_as_float(u.x & 0xFFFF0000u);
      a[2] += __uint_as_float(u.y << 16);
      a[3] += __uint_as_float(u.y & 0xFFFF0000u);
    }
  }
}

// ---------------- APPNP step (mid): hs_out = bf16(0.5*nrm^2*acc + 0.5*hs0) ----------------
__global__ __launch_bounds__(256) void k_gather_mid(const int* __restrict__ perm, const int* __restrict__ row_start,
                                                    const int* __restrict__ deg, const int* __restrict__ csr_src,
                                                    const unsigned short* __restrict__ hs_in,
                                                    const float* __restrict__ nrm,
                                                    const unsigned short* __restrict__ hs0,
                                                    unsigned short* __restrict__ hs_out) {
  int wid = threadIdx.x >> 6, lane = threadIdx.x & 63;
  int n, k; float a[4];
  gather4(perm, row_start, deg, csr_src, hs_in, wid, lane, n, k, a);
  size_t o = (size_t)n * 64 + (k << 2);
  float nn_ = nrm[n];
  float hnn = 0.5f * nn_ * nn_;
  uint2 z = *(const uint2*)&hs0[o];
  ushort4 ov;
  ov.x = f2b(fmaf(hnn, a[0], 0.5f * __uint_as_float(z.x << 16)));
  ov.y = f2b(fmaf(hnn, a[1], 0.5f * __uint_as_float(z.x & 0xFFFF0000u)));
  ov.z = f2b(fmaf(hnn, a[2], 0.5f * __uint_as_float(z.y << 16)));
  ov.w = f2b(fmaf(hnn, a[3], 0.5f * __uint_as_float(z.y & 0xFFFF0000u)));
  *(ushort4*)&hs_out[o] = ov;
}

// ---------------- APPNP step (last) fused with final residual add: h0io = appnp + res2 (f32) ----------------
__global__ __launch_bounds__(256) void k_gather_last(const int* __restrict__ perm, const int* __restrict__ row_start,
                                                     const int* __restrict__ deg, const int* __restrict__ csr_src,
                                                     const unsigned short* __restrict__ hs_in,
                                                     const float* __restrict__ nrm,
                                                     const float* __restrict__ res2,
                                                     float* h0io) {
  int wid = threadIdx.x >> 6, lane = threadIdx.x & 63;
  int n, k; float a[4];
  gather4(perm, row_start, deg, csr_src, hs_in, wid, lane, n, k, a);
  size_t o = (size_t)n * 64 + (k << 2);
  float nn_ = nrm[n];
  float hn = 0.5f * nn_;
  float4 h4 = *(const float4*)&h0io[o];
  float4 r4 = *(const float4*)&res2[o];
  float4 v;
  v.x = fmaf(hn, a[0], 0.5f * h4.x) + r4.x;
  v.y = fmaf(hn, a[1], 0.5f * h4.y) + r4.y;
  v.z = fmaf(hn, a[2], 0.5f * h4.z) + r4.z;
  v.w = fmaf(hn, a[3], 0.5f * h4.w) + r4.w;
  *(float4*)&h0io[o] = v;
}

// ---------------- BN partial sums (pure reduction over hfin f32) ----------------
__global__ __launch_bounds__(256) void k_finred(const float* __restrict__ hfin, float* __restrict__ bn) {
  __shared__ float s1[256], s2[256];
  int d = threadIdx.x & 63;
  int rb = blockIdx.x * 64;
  float sum = 0.f, sq = 0.f;
  for (int r = threadIdx.x >> 6; r < 64; r += 4) {
    int n = rb + r;
    if (n < NN) {
      float v = hfin[(size_t)n * 64 + d];
      sum += v; sq += v * v;
    }
  }
  s1[threadIdx.x] = sum; s2[threadIdx.x] = sq;
  __syncthreads();
  if (threadIdx.x < 128) { s1[threadIdx.x] += s1[threadIdx.x + 128]; s2[threadIdx.x] += s2[threadIdx.x + 128]; }
  __syncthreads();
  if (threadIdx.x < 64) {
    atomicAdd(&bn[d], s1[threadIdx.x] + s1[threadIdx.x + 64]);
    atomicAdd(&bn[64 + d], s2[threadIdx.x] + s2[threadIdx.x + 64]);
  }
}

__global__ void k_bnstats(const float* __restrict__ bn, const float* __restrict__ gamma,
                          const float* __restrict__ beta, float* __restrict__ bns) {
  int d = threadIdx.x;
  float mu = bn[d] * (1.0f / NN);
  float var = fmaxf(bn[64 + d] * (1.0f / NN) - mu * mu, 0.f);
  float sc = rsqrtf(var + 1e-5f) * gamma[d];
  bns[d] = sc;
  bns[64 + d] = beta[d] - mu * sc;
}

__global__ __launch_bounds__(256) void k_bnapply(const float* __restrict__ h, const float* __restrict__ bns,
                                                 float* __restrict__ out) {
  int i = blockIdx.x * 256 + threadIdx.x;
  if (i < NN * 64) {
    int d = i & 63;
    out[i] = fmaf(h[i], bns[d], bns[64 + d]);
  }
}

extern "C" void kernel_launch(void* const* d_in, const int* in_sizes, int n_in,
                              void* d_out, int out_size, void* d_ws, size_t ws_size,
                              hipStream_t stream) {
  const float* node_feats = (const float*)d_in[0];
  const int* src = (const int*)d_in[1];
  const int* dst = (const int*)d_in[2];
  const float* W_fc = (const float*)d_in[3];
  const float* attn_l = (const float*)d_in[4];
  const float* attn_r = (const float*)d_in[5];
  const float* W_res_gat = (const float*)d_in[6];
  const float* gat_bias = (const float*)d_in[7];
  const float* conv_w = (const float*)d_in[8];
  const float* conv_b = (const float*)d_in[9];
  const float* W_res = (const float*)d_in[10];
  const float* b_res = (const float*)d_in[11];
  const float* gamma = (const float*)d_in[12];
  const float* beta = (const float*)d_in[13];
  float* out = (float*)d_out;

  char* base = (char*)d_ws;
  size_t off = 0;
  auto alloc = [&](size_t bytes) -> char* {
    char* p = base + off;
    off = (off + bytes + 255) & ~(size_t)255;
    return p;
  };
  unsigned* feat8u        = (unsigned*)alloc((size_t)NN * 256);                  // 25.6 MB fp8 (n,d,h)
  unsigned short* resval2 = (unsigned short*)alloc((size_t)NN * 256 * 2);        // 51.2 MB bf16; res2 f32 aliases after k_gat
  float* res2             = (float*)resval2;
  float* el               = (float*)alloc((size_t)NN * 4 * 4);
  float* er               = (float*)alloc((size_t)NN * 4 * 4);
  float* h0               = (float*)alloc((size_t)NN * 64 * 4);                  // 25.6 MB; Abf aliases BEFORE k_gat; hfin at end
  unsigned short* Abf     = (unsigned short*)h0;
  unsigned short* hs0     = (unsigned short*)alloc((size_t)(NN + 1) * 64 * 2);   // 12.8 MB bf16(h0*nrm) + dummy row
  unsigned short* hsA     = (unsigned short*)alloc((size_t)(NN + 1) * 64 * 2);
  unsigned short* hsB     = (unsigned short*)alloc((size_t)(NN + 1) * 64 * 2);
  int* csr_src            = (int*)alloc((size_t)NE * 4);
  float* nrm              = (float*)alloc((size_t)NN * 4);
  int* row_start          = (int*)alloc((size_t)NN * 4);
  int* perm               = (int*)alloc((size_t)NN * 4);
  int* dbase              = (int*)alloc(64 * 4);
  unsigned short* Bpacked = (unsigned short*)alloc((size_t)4 * 16384 * 2);
  float* w_elr            = (float*)alloc((size_t)8 * 128 * 4);
  size_t zoff = off;
  int* deg                = (int*)alloc((size_t)NN * 4);
  int* cursor             = (int*)alloc((size_t)NN * 4);
  int* counter            = (int*)alloc(256);
  int* dcount             = (int*)alloc(64 * 4);
  int* dcur               = (int*)alloc(64 * 4);
  float* bn               = (float*)alloc(256 * 4);
  float* hfin             = h0;

  int zwords = (int)((off - zoff) / 4);
  int gE = (NE + 255) / 256;
  int gN = (NN + 255) / 256;
  int gP = NN / 16;  // 6250, exact
  int gM = (NN + 63) / 64;
  int gV = (NN * 64 + 255) / 256;

  k_zero<<<(zwords + 255) / 256, 256, 0, stream>>>((int*)(base + zoff), zwords);
  k_zrow<<<1, 64, 0, stream>>>(hs0, hsA, hsB);
  k_deg<<<gE, 256, 0, stream>>>(dst, deg);
  k_alloc<<<gN, 256, 0, stream>>>(deg, row_start, counter, nrm, dcount);
  k_dbase<<<1, 64, 0, stream>>>(dcount, dbase);
  k_dperm<<<gN, 256, 0, stream>>>(deg, dbase, dcur, perm);
  k_scatter<<<gE, 256, 0, stream>>>(src, dst, row_start, cursor, csr_src);

  k_cast<<<(NN * 128 / 4 + 255) / 256, 256, 0, stream>>>(node_feats, Abf);
  k_prepB<<<dim3(8, 4), 256, 0, stream>>>(W_fc, W_res_gat, Bpacked);
  k_prepw<<<4, 256, 0, stream>>>(W_fc, attn_l, attn_r, w_elr);
  k_gemm_mfma<<<dim3((NN + 127) / 128, 4), 256, 0, stream>>>(Abf, Bpacked, feat8u, resval2);

  k_elr2<<<(NN + 31) / 32, 256, 0, stream>>>(Abf, w_elr, el, er);
  k_gat<<<gP, 256, 0, stream>>>(perm, row_start, deg, csr_src, el, er, feat8u, resval2,
                                gat_bias, conv_w, conv_b, nrm, h0, hs0);

  // resval2 dead now; res2 (f32) reuses its space
  k_gemm_nt_bias_relu<<<gM, 256, 0, stream>>>(node_feats, W_res, b_res, res2);

  k_gather_mid<<<gP, 256, 0, stream>>>(perm, row_start, deg, csr_src, hs0, nrm, hs0, hsA);
  k_gather_mid<<<gP, 256, 0, stream>>>(perm, row_start, deg, csr_src, hsA, nrm, hs0, hsB);
  k_gather_mid<<<gP, 256, 0, stream>>>(perm, row_start, deg, csr_src, hsB, nrm, hs0, hsA);
  k_gather_mid<<<gP, 256, 0, stream>>>(perm, row_start, deg, csr_src, hsA, nrm, hs0, hsB);
  // last step fused with residual add: writes hfin (= h0) in f32
  k_gather_last<<<gP, 256, 0, stream>>>(perm, row_start, deg, csr_src, hsB, nrm, res2, hfin);

  k_finred<<<gM, 256, 0, stream>>>(hfin, bn);
  k_bnstats<<<1, 64, 0, stream>>>(bn, gamma, beta, bn + 128);
  k_bnapply<<<gV, 256, 0, stream>>>(hfin, bn + 128, out);
}

// Round 5
// 734.279 us; speedup vs baseline: 1.6990x; 1.6990x over previous
//
#include <hip/hip_runtime.h>
#include <math.h>

#define NN 100000
#define NE 1600000
#define NEG_SLOPE 0.2f
#define GB 98  // ceil(NN/1024) histogram/scan blocks

typedef __attribute__((ext_vector_type(8))) short bf16x8;
typedef __attribute__((ext_vector_type(4))) float f32x4;
typedef __attribute__((ext_vector_type(2))) float f32x2;

__device__ __forceinline__ float b2f(unsigned short u) {
  union { unsigned u; float f; } c; c.u = ((unsigned)u) << 16; return c.f;
}
__device__ __forceinline__ unsigned short f2b(float x) {
  union { float f; unsigned u; } c; c.f = x;
  unsigned r = c.u + 0x7FFFu + ((c.u >> 16) & 1u);
  return (unsigned short)(r >> 16);
}
__device__ __forceinline__ void fma4(float4& acc, float s, const float4& b) {
  acc.x = fmaf(s, b.x, acc.x);
  acc.y = fmaf(s, b.y, acc.y);
  acc.z = fmaf(s, b.z, acc.z);
  acc.w = fmaf(s, b.w, acc.w);
}

// ---------------- utility ----------------
__global__ __launch_bounds__(256) void k_zero(int* __restrict__ p, int nwords) {
  int i = blockIdx.x * 256 + threadIdx.x;
  if (i < nwords) p[i] = 0;
}

// zero the dummy rows (index NN) of the bf16 buffers
__global__ void k_zrow(unsigned short* __restrict__ a, unsigned short* __restrict__ b,
                       unsigned short* __restrict__ c) {
  int i = threadIdx.x;
  a[(size_t)NN * 64 + i] = 0;
  b[(size_t)NN * 64 + i] = 0;
  c[(size_t)NN * 64 + i] = 0;
}

__global__ __launch_bounds__(256) void k_cast(const float* __restrict__ A, unsigned short* __restrict__ Ab) {
  int i = blockIdx.x * 256 + threadIdx.x;
  int i4 = i * 4;
  if (i4 < NN * 128) {
    float4 v = *(const float4*)&A[i4];
    ushort4 o; o.x = f2b(v.x); o.y = f2b(v.y); o.z = f2b(v.z); o.w = f2b(v.w);
    *(ushort4*)&Ab[i4] = o;
  }
}

// ---------------- CSR build (unordered within row) ----------------
__global__ __launch_bounds__(256) void k_deg(const int* __restrict__ dst, int* __restrict__ deg) {
  int i = blockIdx.x * 256 + threadIdx.x;
  if (i < NE) atomicAdd(&deg[dst[i]], 1);
}

// per-block (1024 nodes) LDS degree histogram + block degree sum; NO global atomics
__global__ __launch_bounds__(256) void k_hist(const int* __restrict__ deg, int* __restrict__ bcount,
                                              int* __restrict__ bsum) {
  __shared__ int hist[64];
  __shared__ int red[256];
  int tid = threadIdx.x, blk = blockIdx.x;
  if (tid < 64) hist[tid] = 0;
  __syncthreads();
  int i0 = blk * 1024 + tid * 4;
  int s = 0;
#pragma unroll
  for (int r = 0; r < 4; ++r) {
    int i = i0 + r;
    if (i < NN) {
      int d = deg[i];
      s += d;
      atomicAdd(&hist[d < 63 ? d : 63], 1);
    }
  }
  red[tid] = s;
  __syncthreads();
  if (tid < 128) red[tid] += red[tid + 128];
  __syncthreads();
  if (tid < 64) {
    int v = red[tid] + red[tid + 64];
#pragma unroll
    for (int off = 32; off > 0; off >>= 1) v += __shfl_xor(v, off, 64);
    if (tid == 0) bsum[blk] = v;
    bcount[blk * 64 + tid] = hist[tid];
  }
}

// exclusive scans: per-bucket across blocks (bcount in-place), bucket bases, block row bases
__global__ void k_scan(int* __restrict__ bcount, const int* __restrict__ bsum,
                       int* __restrict__ dbase, int* __restrict__ bbase) {
  __shared__ int tot[64];
  int tid = threadIdx.x;  // 64 threads
  {
    int s = 0;
#pragma unroll 7
    for (int blk = 0; blk < GB; ++blk) {
      int v = bcount[blk * 64 + tid];
      bcount[blk * 64 + tid] = s;
      s += v;
    }
    tot[tid] = s;
  }
  __syncthreads();
  if (tid == 0) {
    int base = 0;
    for (int b = 0; b < 64; ++b) { dbase[b] = base; base += tot[b]; }
  }
  if (tid == 1) {
    int s = 0;
#pragma unroll 7
    for (int blk = 0; blk < GB; ++blk) { bbase[blk] = s; s += bsum[blk]; }
  }
}

// row_start (block-local LDS scan + bbase), nrm, and degree-sorted perm; only LDS atomics
__global__ __launch_bounds__(256) void k_rows(const int* __restrict__ deg, const int* __restrict__ bcount,
                                              const int* __restrict__ dbase, const int* __restrict__ bbase,
                                              int* __restrict__ row_start, float* __restrict__ nrm,
                                              int* __restrict__ perm) {
  __shared__ int hist[64];
  __shared__ int sc[256];
  int tid = threadIdx.x, blk = blockIdx.x;
  if (tid < 64) hist[tid] = 0;
  int i0 = blk * 1024 + tid * 4;
  int d[4];
#pragma unroll
  for (int r = 0; r < 4; ++r) d[r] = (i0 + r < NN) ? deg[i0 + r] : 0;
  int ts = d[0] + d[1] + d[2] + d[3];
  sc[tid] = ts;
  __syncthreads();
  for (int off = 1; off < 256; off <<= 1) {
    int v = (tid >= off) ? sc[tid - off] : 0;
    __syncthreads();
    sc[tid] += v;
    __syncthreads();
  }
  int base = bbase[blk] + sc[tid] - ts;
#pragma unroll
  for (int r = 0; r < 4; ++r) {
    int i = i0 + r;
    if (i < NN) {
      row_start[i] = base;
      nrm[i] = rsqrtf(fmaxf((float)d[r], 1.0f));
      base += d[r];
      int b = d[r] < 63 ? d[r] : 63;
      int rank = atomicAdd(&hist[b], 1);
      perm[dbase[b] + bcount[blk * 64 + b] + rank] = i;
    }
  }
}

__global__ __launch_bounds__(256) void k_scatter(const int* __restrict__ src, const int* __restrict__ dst,
                                                 const int* __restrict__ row_start, int* __restrict__ cursor,
                                                 int* __restrict__ csr_src) {
  int i = blockIdx.x * 256 + threadIdx.x;
  if (i < NE) {
    int n = dst[i];
    int p = atomicAdd(&cursor[n], 1);
    csr_src[row_start[n] + p] = src[i];
  }
}

// ---------------- fold attention vectors into W_fc: w[p][k], p = side*4+h ----------------
__global__ __launch_bounds__(256) void k_prepw(const float* __restrict__ W_fc, const float* __restrict__ al,
                                               const float* __restrict__ ar, float* __restrict__ w) {
  int o = blockIdx.x * 256 + threadIdx.x;  // [0,1024)
  if (o >= 1024) return;
  int side = o >> 9;
  int h = (o >> 7) & 3;
  int k = o & 127;
  const float* a = side ? ar : al;
  float s = 0.f;
  for (int d = 0; d < 64; ++d) s += W_fc[k * 256 + h * 64 + d] * a[h * 64 + d];
  w[(side * 4 + h) * 128 + k] = s;
}

// ---------------- exact el/er GEMV from bf16 features: thread = (node, p) ----------------
__global__ __launch_bounds__(256) void k_elr2(const unsigned short* __restrict__ X, const float* __restrict__ w,
                                              float* __restrict__ el, float* __restrict__ er) {
  int n = blockIdx.x * 32 + (threadIdx.x >> 3);
  int p = threadIdx.x & 7;
  if (n >= NN) return;
  const uint4* xr = (const uint4*)(X + (size_t)n * 128);
  const float4* wr = (const float4*)(w + p * 128);
  float s = 0.f;
#pragma unroll
  for (int i = 0; i < 16; ++i) {
    uint4 x = xr[i];
    float4 w0 = wr[2 * i], w1 = wr[2 * i + 1];
    s += __uint_as_float(x.x << 16) * w0.x + __uint_as_float(x.x & 0xFFFF0000u) * w0.y
       + __uint_as_float(x.y << 16) * w0.z + __uint_as_float(x.y & 0xFFFF0000u) * w0.w
       + __uint_as_float(x.z << 16) * w1.x + __uint_as_float(x.z & 0xFFFF0000u) * w1.y
       + __uint_as_float(x.w << 16) * w1.z + __uint_as_float(x.w & 0xFFFF0000u) * w1.w;
  }
  if (p < 4) el[n * 4 + p] = s;
  else er[n * 4 + (p - 4)] = s;
}

// ---------------- pre-pack B (both weight mats) into MFMA fragment order ----------------
// layout: [y][kt][nt][quad*16+nn][j]  (kt outer so each kt-pair half is contiguous 16 KB)
__global__ __launch_bounds__(256) void k_prepB(const float* __restrict__ W_fc, const float* __restrict__ W_rg,
                                               unsigned short* __restrict__ Bp) {
  int y = blockIdx.y;
  const float* Bsrc = (y >> 1) ? W_rg : W_fc;
  int colbase = (y & 1) * 128;
  for (int e = blockIdx.x * 256 + threadIdx.x; e < 16384; e += 2048) {
    int n = e & 127, k = e >> 7;
    int p = colbase + n;
    int d = p >> 2, hh = p & 3;
    float v = Bsrc[k * 256 + hh * 64 + d];
    int nt = n >> 4, nn = n & 15, kt = k >> 5, quad = (k >> 3) & 3, j = k & 7;
    Bp[(size_t)y * 16384 + ((kt * 8 + nt) * 64 + quad * 16 + nn) * 8 + j] = f2b(v);
  }
}

// ---------------- merged bf16 MFMA GEMM (LDS-staged A, coalesced epilogue) ----------------
// y=0,1 -> feat8 (fp8, (n,d,h) interleaved); y=2,3 -> resval2 (bf16 interleaved)
__global__ __launch_bounds__(256) void k_gemm_mfma(const unsigned short* __restrict__ Abf,
                                                   const unsigned short* __restrict__ Bp,
                                                   unsigned* __restrict__ feat8u,
                                                   unsigned short* __restrict__ resval2) {
  __shared__ unsigned short Al[128 * 136];  // A tile, 272-B row stride (pad kills bank conflicts)
  __shared__ unsigned short Bl[8192];       // B kt-pair half (16 KB)
  int tid = threadIdx.x;
  int half = blockIdx.y >> 1;
  int colbase = (blockIdx.y & 1) * 128;
  int row0 = blockIdx.x * 128;
  // stage A: 2048 chunks of 16 B, fully coalesced
#pragma unroll
  for (int i = 0; i < 8; ++i) {
    int c = tid + i * 256;
    int row = c >> 4, part = c & 15;
    int gr = row0 + row; if (gr > NN - 1) gr = NN - 1;
    *(uint4*)&Al[row * 136 + part * 8] = *(const uint4*)&Abf[(size_t)gr * 128 + part * 8];
  }
  // stage B half 0 (kt = 0,1)
  {
    const uint4* srcb = (const uint4*)(Bp + (size_t)blockIdx.y * 16384);
    uint4* dst4 = (uint4*)Bl;
#pragma unroll
    for (int i = 0; i < 4; ++i) dst4[tid + i * 256] = srcb[tid + i * 256];
  }
  __syncthreads();
  int w = tid >> 6, lane = tid & 63;
  int quad = lane >> 4, l16 = lane & 15;
  f32x4 acc[8][2];
#pragma unroll
  for (int rt = 0; rt < 8; ++rt)
#pragma unroll
    for (int c = 0; c < 2; ++c) acc[rt][c] = (f32x4){0.f, 0.f, 0.f, 0.f};
#pragma unroll
  for (int kh = 0; kh < 2; ++kh) {
    if (kh == 1) {
      __syncthreads();  // everyone done reading B half 0
      const uint4* srcb = (const uint4*)(Bp + (size_t)blockIdx.y * 16384 + 8192);
      uint4* dst4 = (uint4*)Bl;
#pragma unroll
      for (int i = 0; i < 4; ++i) dst4[tid + i * 256] = srcb[tid + i * 256];
      __syncthreads();
    }
#pragma unroll
    for (int ktl = 0; ktl < 2; ++ktl) {
      int kt = kh * 2 + ktl;
      bf16x8 b0 = *(const bf16x8*)&Bl[((ktl * 8 + w * 2 + 0) * 64 + lane) * 8];
      bf16x8 b1 = *(const bf16x8*)&Bl[((ktl * 8 + w * 2 + 1) * 64 + lane) * 8];
      int kb = kt * 32 + quad * 8;
#pragma unroll
      for (int rt = 0; rt < 8; ++rt) {
        bf16x8 a = *(const bf16x8*)&Al[(rt * 16 + l16) * 136 + kb];
        acc[rt][0] = __builtin_amdgcn_mfma_f32_16x16x32_bf16(b0, a, acc[rt][0], 0, 0, 0);
        acc[rt][1] = __builtin_amdgcn_mfma_f32_16x16x32_bf16(b1, a, acc[rt][1], 0, 0, 0);
      }
    }
  }
  __syncthreads();  // Al/Bl reads done; reuse Al for epilogue staging
  if (half == 0) {
    unsigned* Cl = (unsigned*)Al;  // [128][36] dwords (pad 32->36)
#pragma unroll
    for (int rt = 0; rt < 8; ++rt)
#pragma unroll
      for (int c = 0; c < 2; ++c) {
        int pk = __builtin_amdgcn_cvt_pk_fp8_f32(acc[rt][c][0], acc[rt][c][1], 0, false);
        pk = __builtin_amdgcn_cvt_pk_fp8_f32(acc[rt][c][2], acc[rt][c][3], pk, true);
        Cl[(rt * 16 + l16) * 36 + (w * 2 + c) * 4 + quad] = (unsigned)pk;
      }
    __syncthreads();
#pragma unroll
    for (int i = 0; i < 4; ++i) {
      int c = tid + i * 256;        // 1024 chunks: 128 rows x 8 uint4
      int row = c >> 3, wp = c & 7;
      int m = row0 + row;
      if (m < NN)
        *(uint4*)&feat8u[(size_t)m * 64 + (colbase >> 2) + wp * 4] = *(const uint4*)&Cl[row * 36 + wp * 4];
    }
  } else {
#pragma unroll
    for (int rt = 0; rt < 8; ++rt)
#pragma unroll
      for (int c = 0; c < 2; ++c) {
        int col = (w * 2 + c) * 16 + quad * 4;
        ushort4 o;
        o.x = f2b(acc[rt][c][0]); o.y = f2b(acc[rt][c][1]);
        o.z = f2b(acc[rt][c][2]); o.w = f2b(acc[rt][c][3]);
        *(ushort4*)&Al[(rt * 16 + l16) * 136 + col] = o;
      }
    __syncthreads();
#pragma unroll
    for (int i = 0; i < 8; ++i) {
      int c = tid + i * 256;        // 2048 chunks: 128 rows x 16 uint4
      int row = c >> 4, part = c & 15;
      int m = row0 + row;
      if (m < NN)
        *(uint4*)&resval2[(size_t)m * 256 + colbase + part * 8] = *(const uint4*)&Al[row * 136 + part * 8];
    }
  }
}

// ---------------- res2_f32[N x 64] = relu(A[N x 128] * W_res^T + b_res) (fp32 VALU) ----------------
__global__ __launch_bounds__(256) void k_gemm_nt_bias_relu(const float* __restrict__ A, const float* __restrict__ B,
                                                           const float* __restrict__ bias, float* __restrict__ C) {
  __shared__ float Bl[128][68];
  for (int idx = threadIdx.x; idx < 64 * 128; idx += 256) {
    int d = idx >> 7, k = idx & 127;
    Bl[k][d] = B[d * 128 + k];
  }
  __syncthreads();
  int tx = threadIdx.x & 15, ty = threadIdx.x >> 4;
  int row0 = blockIdx.x * 64 + ty * 4;
  const float* ap[4];
#pragma unroll
  for (int r = 0; r < 4; ++r) ap[r] = A + (size_t)min(row0 + r, NN - 1) * 128;
  float4 acc[4];
#pragma unroll
  for (int r = 0; r < 4; ++r) acc[r] = make_float4(0.f, 0.f, 0.f, 0.f);
#pragma unroll 2
  for (int k0 = 0; k0 < 128; k0 += 4) {
    float4 b0 = *(const float4*)&Bl[k0][tx * 4];
    float4 b1 = *(const float4*)&Bl[k0 + 1][tx * 4];
    float4 b2 = *(const float4*)&Bl[k0 + 2][tx * 4];
    float4 b3 = *(const float4*)&Bl[k0 + 3][tx * 4];
#pragma unroll
    for (int r = 0; r < 4; ++r) {
      float4 a = *(const float4*)(ap[r] + k0);
      fma4(acc[r], a.x, b0); fma4(acc[r], a.y, b1);
      fma4(acc[r], a.z, b2); fma4(acc[r], a.w, b3);
    }
  }
  float4 bv = *(const float4*)&bias[tx * 4];
#pragma unroll
  for (int r = 0; r < 4; ++r) {
    int row = row0 + r;
    if (row < NN) {
      float4 v;
      v.x = fmaxf(acc[r].x + bv.x, 0.f);
      v.y = fmaxf(acc[r].y + bv.y, 0.f);
      v.z = fmaxf(acc[r].z + bv.z, 0.f);
      v.w = fmaxf(acc[r].w + bv.w, 0.f);
      *(float4*)&C[(size_t)row * 64 + tx * 4] = v;
    }
  }
}

// ---------------- fused edge-softmax + aggregation + relu + head-mix conv ----------------
// 4 nodes per wave (degree-sorted via perm), 16 lanes per node, lane k owns dims 4k..4k+3.
__global__ __launch_bounds__(256) void k_gat(const int* __restrict__ perm, const int* __restrict__ row_start,
                                             const int* __restrict__ deg, const int* __restrict__ csr_src,
                                             const float* __restrict__ el, const float* __restrict__ er,
                                             const unsigned* __restrict__ feat8u,
                                             const unsigned short* __restrict__ resval2,
                                             const float* __restrict__ gat_bias, const float* __restrict__ conv_w,
                                             const float* __restrict__ conv_b, const float* __restrict__ nrm,
                                             float* __restrict__ h0, unsigned short* __restrict__ hs0o) {
  __shared__ int s_src[4][4][16];
  __shared__ float s_x[4][4][16][4];
  int wid = threadIdx.x >> 6, lane = threadIdx.x & 63;
  int g = lane >> 4, k = lane & 15;
  int n = perm[blockIdx.x * 16 + wid * 4 + g];   // grid*16 == NN exactly
  int s0 = row_start[n], cnt = deg[n];
  float4 er4 = *(const float4*)&er[n * 4];
  unsigned koff = (unsigned)(k << 4);
  f32x2 a01[4], a23[4];
#pragma unroll
  for (int i = 0; i < 4; ++i) { a01[i] = (f32x2){0.f, 0.f}; a23[i] = (f32x2){0.f, 0.f}; }
  f32x2 den01 = (f32x2){0.f, 0.f}, den23 = (f32x2){0.f, 0.f};
  int cm = cnt;
  cm = max(cm, __shfl_xor(cm, 16, 64));
  cm = max(cm, __shfl_xor(cm, 32, 64));
  for (int base = 0; base < cm; base += 16) {
    int j = base + k;
    int s = 0;
    float x0 = 0.f, x1 = 0.f, x2 = 0.f, x3 = 0.f;
    if (j < cnt) {
      s = csr_src[s0 + j];
      float4 el4 = *(const float4*)&el[s * 4];
      float e0 = el4.x + er4.x; e0 = (e0 > 0.f) ? e0 : NEG_SLOPE * e0;
      float e1 = el4.y + er4.y; e1 = (e1 > 0.f) ? e1 : NEG_SLOPE * e1;
      float e2 = el4.z + er4.z; e2 = (e2 > 0.f) ? e2 : NEG_SLOPE * e2;
      float e3 = el4.w + er4.w; e3 = (e3 > 0.f) ? e3 : NEG_SLOPE * e3;
      x0 = __expf(e0); x1 = __expf(e1); x2 = __expf(e2); x3 = __expf(e3);
    }
    s_src[wid][g][k] = s;
    *(float4*)&s_x[wid][g][k][0] = make_float4(x0, x1, x2, x3);
    den01 += (f32x2){x0, x1}; den23 += (f32x2){x2, x3};
    int tm = cm - base; if (tm > 16) tm = 16;
    for (int t = 0; t < tm; ++t) {
      int s_ = s_src[wid][g][t];
      float4 x4 = *(const float4*)&s_x[wid][g][t][0];
      uint4 f = *(const uint4*)((const char*)feat8u + (((unsigned)s_ << 8) + koff));
      f32x2 x01 = (f32x2){x4.x, x4.y}, x23 = (f32x2){x4.z, x4.w};
      f32x2 lo, hi;
      lo = __builtin_amdgcn_cvt_pk_f32_fp8((int)f.x, false);
      hi = __builtin_amdgcn_cvt_pk_f32_fp8((int)f.x, true);
      a01[0] += x01 * lo; a23[0] += x23 * hi;
      lo = __builtin_amdgcn_cvt_pk_f32_fp8((int)f.y, false);
      hi = __builtin_amdgcn_cvt_pk_f32_fp8((int)f.y, true);
      a01[1] += x01 * lo; a23[1] += x23 * hi;
      lo = __builtin_amdgcn_cvt_pk_f32_fp8((int)f.z, false);
      hi = __builtin_amdgcn_cvt_pk_f32_fp8((int)f.z, true);
      a01[2] += x01 * lo; a23[2] += x23 * hi;
      lo = __builtin_amdgcn_cvt_pk_f32_fp8((int)f.w, false);
      hi = __builtin_amdgcn_cvt_pk_f32_fp8((int)f.w, true);
      a01[3] += x01 * lo; a23[3] += x23 * hi;
    }
  }
  // den reduce within each 16-lane group
#pragma unroll
  for (int off = 1; off < 16; off <<= 1) {
    den01[0] += __shfl_xor(den01[0], off, 64);
    den01[1] += __shfl_xor(den01[1], off, 64);
    den23[0] += __shfl_xor(den23[0], off, 64);
    den23[1] += __shfl_xor(den23[1], off, 64);
  }
  float i0 = 1.f / fmaxf(den01[0], 1e-9f);
  float i1 = 1.f / fmaxf(den01[1], 1e-9f);
  float i2 = 1.f / fmaxf(den23[0], 1e-9f);
  float i3 = 1.f / fmaxf(den23[1], 1e-9f);
  // epilogue: lane k handles dims 4k..4k+3 of node n
  uint4 rv0 = *(const uint4*)&resval2[(size_t)n * 256 + (k << 4)];
  uint4 rv1 = *(const uint4*)&resval2[(size_t)n * 256 + (k << 4) + 8];
  unsigned short c[16];
  *(uint4*)&c[0] = rv0; *(uint4*)&c[8] = rv1;
  int d0 = k << 2;
  float4 b0 = *(const float4*)&gat_bias[d0];
  float4 b1 = *(const float4*)&gat_bias[64 + d0];
  float4 b2 = *(const float4*)&gat_bias[128 + d0];
  float4 b3 = *(const float4*)&gat_bias[192 + d0];
  float bh0[4] = {b0.x, b0.y, b0.z, b0.w};
  float bh1[4] = {b1.x, b1.y, b1.z, b1.w};
  float bh2[4] = {b2.x, b2.y, b2.z, b2.w};
  float bh3[4] = {b3.x, b3.y, b3.z, b3.w};
  float cb = conv_b[0];
  float cw0 = conv_w[0], cw1 = conv_w[1], cw2 = conv_w[2], cw3 = conv_w[3];
  float hm[4];
#pragma unroll
  for (int i = 0; i < 4; ++i) {
    float t_, hmv = cb;
    t_ = fmaf(a01[i][0], i0, b2f(c[4 * i + 0]) + bh0[i]); t_ = fmaxf(t_, 0.f); hmv = fmaf(cw0, t_, hmv);
    t_ = fmaf(a01[i][1], i1, b2f(c[4 * i + 1]) + bh1[i]); t_ = fmaxf(t_, 0.f); hmv = fmaf(cw1, t_, hmv);
    t_ = fmaf(a23[i][0], i2, b2f(c[4 * i + 2]) + bh2[i]); t_ = fmaxf(t_, 0.f); hmv = fmaf(cw2, t_, hmv);
    t_ = fmaf(a23[i][1], i3, b2f(c[4 * i + 3]) + bh3[i]); t_ = fmaxf(t_, 0.f); hmv = fmaf(cw3, t_, hmv);
    hm[i] = hmv;
  }
  float nn_ = nrm[n];
  size_t o = (size_t)n * 64 + d0;
  *(float4*)&h0[o] = make_float4(hm[0], hm[1], hm[2], hm[3]);
  ushort4 hs;
  hs.x = f2b(hm[0] * nn_); hs.y = f2b(hm[1] * nn_);
  hs.z = f2b(hm[2] * nn_); hs.w = f2b(hm[3] * nn_);
  *(ushort4*)&hs0o[o] = hs;
}

// ---------------- APPNP gather core: 4 nodes/wave, 16 lanes/node, lane owns dims 4k..4k+3 ----------------
__device__ __forceinline__ void gather4(const int* __restrict__ perm, const int* __restrict__ row_start,
                                        const int* __restrict__ deg, const int* __restrict__ csr_src,
                                        const unsigned short* __restrict__ hs_in,
                                        int wid, int lane, int& n, int& k, float (&a)[4]) {
  __shared__ int s_src[4][4][16];
  int g = lane >> 4; k = lane & 15;
  n = perm[blockIdx.x * 16 + wid * 4 + g];
  int s0 = row_start[n], cnt = deg[n];
  unsigned koff = (unsigned)(k << 3);
  a[0] = 0.f; a[1] = 0.f; a[2] = 0.f; a[3] = 0.f;
  int cm = cnt;
  cm = max(cm, __shfl_xor(cm, 16, 64));
  cm = max(cm, __shfl_xor(cm, 32, 64));
  for (int base = 0; base < cm; base += 16) {
    int j = base + k;
    s_src[wid][g][k] = (j < cnt) ? csr_src[s0 + j] : NN;  // row NN is zeroed
    int tm = cm - base; if (tm > 16) tm = 16;
    for (int t = 0; t < tm; ++t) {
      int s = s_src[wid][g][t];
      uint2 u = *(const uint2*)((const char*)hs_in + (((unsigned)s << 7) + koff));
      a[0] += __uint_as_float(u.x << 16);
      a[1] += __uint_as_float(u.x & 0xFFFF0000u);
      a[2] += __uint_as_float(u.y << 16);
      a[3] += __uint_as_float(u.y & 0xFFFF0000u);
    }
  }
}

// ---------------- APPNP step (mid): hs_out = bf16(0.5*nrm^2*acc + 0.5*hs0) ----------------
__global__ __launch_bounds__(256) void k_gather_mid(const int* __restrict__ perm, const int* __restrict__ row_start,
                                                    const int* __restrict__ deg, const int* __restrict__ csr_src,
                                                    const unsigned short* __restrict__ hs_in,
                                                    const float* __restrict__ nrm,
                                                    const unsigned short* __restrict__ hs0,
                                                    unsigned short* __restrict__ hs_out) {
  int wid = threadIdx.x >> 6, lane = threadIdx.x & 63;
  int n, k; float a[4];
  gather4(perm, row_start, deg, csr_src, hs_in, wid, lane, n, k, a);
  size_t o = (size_t)n * 64 + (k << 2);
  float nn_ = nrm[n];
  float hnn = 0.5f * nn_ * nn_;
  uint2 z = *(const uint2*)&hs0[o];
  ushort4 ov;
  ov.x = f2b(fmaf(hnn, a[0], 0.5f * __uint_as_float(z.x << 16)));
  ov.y = f2b(fmaf(hnn, a[1], 0.5f * __uint_as_float(z.x & 0xFFFF0000u)));
  ov.z = f2b(fmaf(hnn, a[2], 0.5f * __uint_as_float(z.y << 16)));
  ov.w = f2b(fmaf(hnn, a[3], 0.5f * __uint_as_float(z.y & 0xFFFF0000u)));
  *(ushort4*)&hs_out[o] = ov;
}

// ---------------- APPNP step (last) fused with final residual add: h0io = appnp + res2 (f32) ----------------
__global__ __launch_bounds__(256) void k_gather_last(const int* __restrict__ perm, const int* __restrict__ row_start,
                                                     const int* __restrict__ deg, const int* __restrict__ csr_src,
                                                     const unsigned short* __restrict__ hs_in,
                                                     const float* __restrict__ nrm,
                                                     const float* __restrict__ res2,
                                                     float* h0io) {
  int wid = threadIdx.x >> 6, lane = threadIdx.x & 63;
  int n, k; float a[4];
  gather4(perm, row_start, deg, csr_src, hs_in, wid, lane, n, k, a);
  size_t o = (size_t)n * 64 + (k << 2);
  float nn_ = nrm[n];
  float hn = 0.5f * nn_;
  float4 h4 = *(const float4*)&h0io[o];
  float4 r4 = *(const float4*)&res2[o];
  float4 v;
  v.x = fmaf(hn, a[0], 0.5f * h4.x) + r4.x;
  v.y = fmaf(hn, a[1], 0.5f * h4.y) + r4.y;
  v.z = fmaf(hn, a[2], 0.5f * h4.z) + r4.z;
  v.w = fmaf(hn, a[3], 0.5f * h4.w) + r4.w;
  *(float4*)&h0io[o] = v;
}

// ---------------- BN partial sums (pure reduction over hfin f32) ----------------
__global__ __launch_bounds__(256) void k_finred(const float* __restrict__ hfin, float* __restrict__ bn) {
  __shared__ float s1[256], s2[256];
  int d = threadIdx.x & 63;
  int rb = blockIdx.x * 64;
  float sum = 0.f, sq = 0.f;
  for (int r = threadIdx.x >> 6; r < 64; r += 4) {
    int n = rb + r;
    if (n < NN) {
      float v = hfin[(size_t)n * 64 + d];
      sum += v; sq += v * v;
    }
  }
  s1[threadIdx.x] = sum; s2[threadIdx.x] = sq;
  __syncthreads();
  if (threadIdx.x < 128) { s1[threadIdx.x] += s1[threadIdx.x + 128]; s2[threadIdx.x] += s2[threadIdx.x + 128]; }
  __syncthreads();
  if (threadIdx.x < 64) {
    atomicAdd(&bn[d], s1[threadIdx.x] + s1[threadIdx.x + 64]);
    atomicAdd(&bn[64 + d], s2[threadIdx.x] + s2[threadIdx.x + 64]);
  }
}

__global__ void k_bnstats(const float* __restrict__ bn, const float* __restrict__ gamma,
                          const float* __restrict__ beta, float* __restrict__ bns) {
  int d = threadIdx.x;
  float mu = bn[d] * (1.0f / NN);
  float var = fmaxf(bn[64 + d] * (1.0f / NN) - mu * mu, 0.f);
  float sc = rsqrtf(var + 1e-5f) * gamma[d];
  bns[d] = sc;
  bns[64 + d] = beta[d] - mu * sc;
}

__global__ __launch_bounds__(256) void k_bnapply(const float* __restrict__ h, const float* __restrict__ bns,
                                                 float* __restrict__ out) {
  int i = blockIdx.x * 256 + threadIdx.x;
  if (i < NN * 64) {
    int d = i & 63;
    out[i] = fmaf(h[i], bns[d], bns[64 + d]);
  }
}

extern "C" void kernel_launch(void* const* d_in, const int* in_sizes, int n_in,
                              void* d_out, int out_size, void* d_ws, size_t ws_size,
                              hipStream_t stream) {
  const float* node_feats = (const float*)d_in[0];
  const int* src = (const int*)d_in[1];
  const int* dst = (const int*)d_in[2];
  const float* W_fc = (const float*)d_in[3];
  const float* attn_l = (const float*)d_in[4];
  const float* attn_r = (const float*)d_in[5];
  const float* W_res_gat = (const float*)d_in[6];
  const float* gat_bias = (const float*)d_in[7];
  const float* conv_w = (const float*)d_in[8];
  const float* conv_b = (const float*)d_in[9];
  const float* W_res = (const float*)d_in[10];
  const float* b_res = (const float*)d_in[11];
  const float* gamma = (const float*)d_in[12];
  const float* beta = (const float*)d_in[13];
  float* out = (float*)d_out;

  char* base = (char*)d_ws;
  size_t off = 0;
  auto alloc = [&](size_t bytes) -> char* {
    char* p = base + off;
    off = (off + bytes + 255) & ~(size_t)255;
    return p;
  };
  unsigned* feat8u        = (unsigned*)alloc((size_t)NN * 256);                  // 25.6 MB fp8 (n,d,h)
  unsigned short* resval2 = (unsigned short*)alloc((size_t)NN * 256 * 2);        // 51.2 MB bf16; res2 f32 aliases after k_gat
  float* res2             = (float*)resval2;
  float* el               = (float*)alloc((size_t)NN * 4 * 4);
  float* er               = (float*)alloc((size_t)NN * 4 * 4);
  float* h0               = (float*)alloc((size_t)NN * 64 * 4);                  // 25.6 MB; Abf aliases BEFORE k_gat; hfin at end
  unsigned short* Abf     = (unsigned short*)h0;
  unsigned short* hs0     = (unsigned short*)alloc((size_t)(NN + 1) * 64 * 2);   // 12.8 MB bf16(h0*nrm) + dummy row
  unsigned short* hsA     = (unsigned short*)alloc((size_t)(NN + 1) * 64 * 2);
  unsigned short* hsB     = (unsigned short*)alloc((size_t)(NN + 1) * 64 * 2);
  int* csr_src            = (int*)alloc((size_t)NE * 4);
  float* nrm              = (float*)alloc((size_t)NN * 4);
  int* row_start          = (int*)alloc((size_t)NN * 4);
  int* perm               = (int*)alloc((size_t)NN * 4);
  int* bcount             = (int*)alloc((size_t)GB * 64 * 4);
  int* bsum               = (int*)alloc((size_t)GB * 4);
  int* bbase              = (int*)alloc((size_t)GB * 4);
  int* dbase              = (int*)alloc(64 * 4);
  unsigned short* Bpacked = (unsigned short*)alloc((size_t)4 * 16384 * 2);
  float* w_elr            = (float*)alloc((size_t)8 * 128 * 4);
  size_t zoff = off;
  int* deg                = (int*)alloc((size_t)NN * 4);
  int* cursor             = (int*)alloc((size_t)NN * 4);
  float* bn               = (float*)alloc(256 * 4);
  float* hfin             = h0;

  int zwords = (int)((off - zoff) / 4);
  int gE = (NE + 255) / 256;
  int gP = NN / 16;  // 6250, exact
  int gM = (NN + 63) / 64;
  int gV = (NN * 64 + 255) / 256;

  k_zero<<<(zwords + 255) / 256, 256, 0, stream>>>((int*)(base + zoff), zwords);
  k_zrow<<<1, 64, 0, stream>>>(hs0, hsA, hsB);
  k_deg<<<gE, 256, 0, stream>>>(dst, deg);
  k_hist<<<GB, 256, 0, stream>>>(deg, bcount, bsum);
  k_scan<<<1, 64, 0, stream>>>(bcount, bsum, dbase, bbase);
  k_rows<<<GB, 256, 0, stream>>>(deg, bcount, dbase, bbase, row_start, nrm, perm);
  k_scatter<<<gE, 256, 0, stream>>>(src, dst, row_start, cursor, csr_src);

  k_cast<<<(NN * 128 / 4 + 255) / 256, 256, 0, stream>>>(node_feats, Abf);
  k_prepB<<<dim3(8, 4), 256, 0, stream>>>(W_fc, W_res_gat, Bpacked);
  k_prepw<<<4, 256, 0, stream>>>(W_fc, attn_l, attn_r, w_elr);
  k_gemm_mfma<<<dim3((NN + 127) / 128, 4), 256, 0, stream>>>(Abf, Bpacked, feat8u, resval2);

  k_elr2<<<(NN + 31) / 32, 256, 0, stream>>>(Abf, w_elr, el, er);
  k_gat<<<gP, 256, 0, stream>>>(perm, row_start, deg, csr_src, el, er, feat8u, resval2,
                                gat_bias, conv_w, conv_b, nrm, h0, hs0);

  // resval2 dead now; res2 (f32) reuses its space
  k_gemm_nt_bias_relu<<<gM, 256, 0, stream>>>(node_feats, W_res, b_res, res2);

  k_gather_mid<<<gP, 256, 0, stream>>>(perm, row_start, deg, csr_src, hs0, nrm, hs0, hsA);
  k_gather_mid<<<gP, 256, 0, stream>>>(perm, row_start, deg, csr_src, hsA, nrm, hs0, hsB);
  k_gather_mid<<<gP, 256, 0, stream>>>(perm, row_start, deg, csr_src, hsB, nrm, hs0, hsA);
  k_gather_mid<<<gP, 256, 0, stream>>>(perm, row_start, deg, csr_src, hsA, nrm, hs0, hsB);
  // last step fused with residual add: writes hfin (= h0) in f32
  k_gather_last<<<gP, 256, 0, stream>>>(perm, row_start, deg, csr_src, hsB, nrm, res2, hfin);

  k_finred<<<gM, 256, 0, stream>>>(hfin, bn);
  k_bnstats<<<1, 64, 0, stream>>>(bn, gamma, beta, bn + 128);
  k_bnapply<<<gV, 256, 0, stream>>>(hfin, bn + 128, out);
}

// Round 6
// 727.650 us; speedup vs baseline: 1.7144x; 1.0091x over previous
//
#include <hip/hip_runtime.h>
#include <math.h>

#define NN 100000
#define NE 1600000
#define NEG_SLOPE 0.2f
#define GB 98      // ceil(NN/1024) histogram/scan blocks
#define GP 6250    // NN/16 gather blocks
#define SCR 2411u  // coprime with 6250 -> bijective block scramble

typedef __attribute__((ext_vector_type(8))) short bf16x8;
typedef __attribute__((ext_vector_type(4))) float f32x4;
typedef __attribute__((ext_vector_type(2))) float f32x2;

__device__ __forceinline__ float b2f(unsigned short u) {
  union { unsigned u; float f; } c; c.u = ((unsigned)u) << 16; return c.f;
}
__device__ __forceinline__ unsigned short f2b(float x) {
  union { float f; unsigned u; } c; c.f = x;
  unsigned r = c.u + 0x7FFFu + ((c.u >> 16) & 1u);
  return (unsigned short)(r >> 16);
}
__device__ __forceinline__ void fma4(float4& acc, float s, const float4& b) {
  acc.x = fmaf(s, b.x, acc.x);
  acc.y = fmaf(s, b.y, acc.y);
  acc.z = fmaf(s, b.z, acc.z);
  acc.w = fmaf(s, b.w, acc.w);
}

// ---------------- utility ----------------
__global__ __launch_bounds__(256) void k_zero(int* __restrict__ p, int nwords) {
  int i = blockIdx.x * 256 + threadIdx.x;
  if (i < nwords) p[i] = 0;
}

// zero the dummy rows (index NN) of the bf16 buffers
__global__ void k_zrow(unsigned short* __restrict__ a, unsigned short* __restrict__ b,
                       unsigned short* __restrict__ c) {
  int i = threadIdx.x;
  a[(size_t)NN * 64 + i] = 0;
  b[(size_t)NN * 64 + i] = 0;
  c[(size_t)NN * 64 + i] = 0;
}

__global__ __launch_bounds__(256) void k_cast(const float* __restrict__ A, unsigned short* __restrict__ Ab) {
  int i = blockIdx.x * 256 + threadIdx.x;
  int i4 = i * 4;
  if (i4 < NN * 128) {
    float4 v = *(const float4*)&A[i4];
    ushort4 o; o.x = f2b(v.x); o.y = f2b(v.y); o.z = f2b(v.z); o.w = f2b(v.w);
    *(ushort4*)&Ab[i4] = o;
  }
}

// ---------------- CSR build (unordered within row) ----------------
__global__ __launch_bounds__(256) void k_deg(const int* __restrict__ dst, int* __restrict__ deg) {
  int i = blockIdx.x * 256 + threadIdx.x;
  if (i < NE) atomicAdd(&deg[dst[i]], 1);
}

// per-block (1024 nodes) LDS degree histogram + block degree sum; NO global atomics
__global__ __launch_bounds__(256) void k_hist(const int* __restrict__ deg, int* __restrict__ bcount,
                                              int* __restrict__ bsum) {
  __shared__ int hist[64];
  __shared__ int red[256];
  int tid = threadIdx.x, blk = blockIdx.x;
  if (tid < 64) hist[tid] = 0;
  __syncthreads();
  int i0 = blk * 1024 + tid * 4;
  int s = 0;
#pragma unroll
  for (int r = 0; r < 4; ++r) {
    int i = i0 + r;
    if (i < NN) {
      int d = deg[i];
      s += d;
      atomicAdd(&hist[d < 63 ? d : 63], 1);
    }
  }
  red[tid] = s;
  __syncthreads();
  if (tid < 128) red[tid] += red[tid + 128];
  __syncthreads();
  if (tid < 64) {
    int v = red[tid] + red[tid + 64];
#pragma unroll
    for (int off = 32; off > 0; off >>= 1) v += __shfl_xor(v, off, 64);
    if (tid == 0) bsum[blk] = v;
    bcount[blk * 64 + tid] = hist[tid];
  }
}

// exclusive scans: per-bucket across blocks (bcount in-place), bucket bases, block row bases
__global__ void k_scan(int* __restrict__ bcount, const int* __restrict__ bsum,
                       int* __restrict__ dbase, int* __restrict__ bbase) {
  __shared__ int tot[64];
  int tid = threadIdx.x;  // 64 threads
  {
    int s = 0;
#pragma unroll 7
    for (int blk = 0; blk < GB; ++blk) {
      int v = bcount[blk * 64 + tid];
      bcount[blk * 64 + tid] = s;
      s += v;
    }
    tot[tid] = s;
  }
  __syncthreads();
  if (tid == 0) {
    int base = 0;
    for (int b = 0; b < 64; ++b) { dbase[b] = base; base += tot[b]; }
  }
  if (tid == 1) {
    int s = 0;
#pragma unroll 7
    for (int blk = 0; blk < GB; ++blk) { bbase[blk] = s; s += bsum[blk]; }
  }
}

// row_start (block-local LDS scan + bbase), nrm, and degree-sorted perm; only LDS atomics
__global__ __launch_bounds__(256) void k_rows(const int* __restrict__ deg, const int* __restrict__ bcount,
                                              const int* __restrict__ dbase, const int* __restrict__ bbase,
                                              int* __restrict__ row_start, float* __restrict__ nrm,
                                              int* __restrict__ perm) {
  __shared__ int hist[64];
  __shared__ int sc[256];
  int tid = threadIdx.x, blk = blockIdx.x;
  if (tid < 64) hist[tid] = 0;
  int i0 = blk * 1024 + tid * 4;
  int d[4];
#pragma unroll
  for (int r = 0; r < 4; ++r) d[r] = (i0 + r < NN) ? deg[i0 + r] : 0;
  int ts = d[0] + d[1] + d[2] + d[3];
  sc[tid] = ts;
  __syncthreads();
  for (int off = 1; off < 256; off <<= 1) {
    int v = (tid >= off) ? sc[tid - off] : 0;
    __syncthreads();
    sc[tid] += v;
    __syncthreads();
  }
  int base = bbase[blk] + sc[tid] - ts;
#pragma unroll
  for (int r = 0; r < 4; ++r) {
    int i = i0 + r;
    if (i < NN) {
      row_start[i] = base;
      nrm[i] = rsqrtf(fmaxf((float)d[r], 1.0f));
      base += d[r];
      int b = d[r] < 63 ? d[r] : 63;
      int rank = atomicAdd(&hist[b], 1);
      perm[dbase[b] + bcount[blk * 64 + b] + rank] = i;
    }
  }
}

__global__ __launch_bounds__(256) void k_scatter(const int* __restrict__ src, const int* __restrict__ dst,
                                                 const int* __restrict__ row_start, int* __restrict__ cursor,
                                                 int* __restrict__ csr_src) {
  int i = blockIdx.x * 256 + threadIdx.x;
  if (i < NE) {
    int n = dst[i];
    int p = atomicAdd(&cursor[n], 1);
    csr_src[row_start[n] + p] = src[i];
  }
}

// ---------------- fold attention vectors into W_fc: w[p][k], p = side*4+h ----------------
__global__ __launch_bounds__(256) void k_prepw(const float* __restrict__ W_fc, const float* __restrict__ al,
                                               const float* __restrict__ ar, float* __restrict__ w) {
  int o = blockIdx.x * 256 + threadIdx.x;  // [0,1024)
  if (o >= 1024) return;
  int side = o >> 9;
  int h = (o >> 7) & 3;
  int k = o & 127;
  const float* a = side ? ar : al;
  float s = 0.f;
  for (int d = 0; d < 64; ++d) s += W_fc[k * 256 + h * 64 + d] * a[h * 64 + d];
  w[(side * 4 + h) * 128 + k] = s;
}

// ---------------- exact el/er GEMV from bf16 features: thread = (node, p) ----------------
__global__ __launch_bounds__(256) void k_elr2(const unsigned short* __restrict__ X, const float* __restrict__ w,
                                              float* __restrict__ el, float* __restrict__ er) {
  int n = blockIdx.x * 32 + (threadIdx.x >> 3);
  int p = threadIdx.x & 7;
  if (n >= NN) return;
  const uint4* xr = (const uint4*)(X + (size_t)n * 128);
  const float4* wr = (const float4*)(w + p * 128);
  float s = 0.f;
#pragma unroll
  for (int i = 0; i < 16; ++i) {
    uint4 x = xr[i];
    float4 w0 = wr[2 * i], w1 = wr[2 * i + 1];
    s += __uint_as_float(x.x << 16) * w0.x + __uint_as_float(x.x & 0xFFFF0000u) * w0.y
       + __uint_as_float(x.y << 16) * w0.z + __uint_as_float(x.y & 0xFFFF0000u) * w0.w
       + __uint_as_float(x.z << 16) * w1.x + __uint_as_float(x.z & 0xFFFF0000u) * w1.y
       + __uint_as_float(x.w << 16) * w1.z + __uint_as_float(x.w & 0xFFFF0000u) * w1.w;
  }
  if (p < 4) el[n * 4 + p] = s;
  else er[n * 4 + (p - 4)] = s;
}

// ---------------- pre-pack B (both weight mats) into MFMA fragment order ----------------
// layout: [y][kt][nt][quad*16+nn][j]  (kt outer so each kt-pair half is contiguous 16 KB)
__global__ __launch_bounds__(256) void k_prepB(const float* __restrict__ W_fc, const float* __restrict__ W_rg,
                                               unsigned short* __restrict__ Bp) {
  int y = blockIdx.y;
  const float* Bsrc = (y >> 1) ? W_rg : W_fc;
  int colbase = (y & 1) * 128;
  for (int e = blockIdx.x * 256 + threadIdx.x; e < 16384; e += 2048) {
    int n = e & 127, k = e >> 7;
    int p = colbase + n;
    int d = p >> 2, hh = p & 3;
    float v = Bsrc[k * 256 + hh * 64 + d];
    int nt = n >> 4, nn = n & 15, kt = k >> 5, quad = (k >> 3) & 3, j = k & 7;
    Bp[(size_t)y * 16384 + ((kt * 8 + nt) * 64 + quad * 16 + nn) * 8 + j] = f2b(v);
  }
}

// ---------------- merged bf16 MFMA GEMM (LDS-staged A, coalesced epilogue) ----------------
// y=0,1 -> feat8 (fp8, (n,d,h) interleaved); y=2,3 -> resval2 (bf16 interleaved)
__global__ __launch_bounds__(256) void k_gemm_mfma(const unsigned short* __restrict__ Abf,
                                                   const unsigned short* __restrict__ Bp,
                                                   unsigned* __restrict__ feat8u,
                                                   unsigned short* __restrict__ resval2) {
  __shared__ unsigned short Al[128 * 136];  // A tile, 272-B row stride (pad kills bank conflicts)
  __shared__ unsigned short Bl[8192];       // B kt-pair half (16 KB)
  int tid = threadIdx.x;
  int half = blockIdx.y >> 1;
  int colbase = (blockIdx.y & 1) * 128;
  int row0 = blockIdx.x * 128;
  // stage A: 2048 chunks of 16 B, fully coalesced
#pragma unroll
  for (int i = 0; i < 8; ++i) {
    int c = tid + i * 256;
    int row = c >> 4, part = c & 15;
    int gr = row0 + row; if (gr > NN - 1) gr = NN - 1;
    *(uint4*)&Al[row * 136 + part * 8] = *(const uint4*)&Abf[(size_t)gr * 128 + part * 8];
  }
  // stage B half 0 (kt = 0,1)
  {
    const uint4* srcb = (const uint4*)(Bp + (size_t)blockIdx.y * 16384);
    uint4* dst4 = (uint4*)Bl;
#pragma unroll
    for (int i = 0; i < 4; ++i) dst4[tid + i * 256] = srcb[tid + i * 256];
  }
  __syncthreads();
  int w = tid >> 6, lane = tid & 63;
  int quad = lane >> 4, l16 = lane & 15;
  f32x4 acc[8][2];
#pragma unroll
  for (int rt = 0; rt < 8; ++rt)
#pragma unroll
    for (int c = 0; c < 2; ++c) acc[rt][c] = (f32x4){0.f, 0.f, 0.f, 0.f};
#pragma unroll
  for (int kh = 0; kh < 2; ++kh) {
    if (kh == 1) {
      __syncthreads();  // everyone done reading B half 0
      const uint4* srcb = (const uint4*)(Bp + (size_t)blockIdx.y * 16384 + 8192);
      uint4* dst4 = (uint4*)Bl;
#pragma unroll
      for (int i = 0; i < 4; ++i) dst4[tid + i * 256] = srcb[tid + i * 256];
      __syncthreads();
    }
#pragma unroll
    for (int ktl = 0; ktl < 2; ++ktl) {
      int kt = kh * 2 + ktl;
      bf16x8 b0 = *(const bf16x8*)&Bl[((ktl * 8 + w * 2 + 0) * 64 + lane) * 8];
      bf16x8 b1 = *(const bf16x8*)&Bl[((ktl * 8 + w * 2 + 1) * 64 + lane) * 8];
      int kb = kt * 32 + quad * 8;
#pragma unroll
      for (int rt = 0; rt < 8; ++rt) {
        bf16x8 a = *(const bf16x8*)&Al[(rt * 16 + l16) * 136 + kb];
        acc[rt][0] = __builtin_amdgcn_mfma_f32_16x16x32_bf16(b0, a, acc[rt][0], 0, 0, 0);
        acc[rt][1] = __builtin_amdgcn_mfma_f32_16x16x32_bf16(b1, a, acc[rt][1], 0, 0, 0);
      }
    }
  }
  __syncthreads();  // Al/Bl reads done; reuse Al for epilogue staging
  if (half == 0) {
    unsigned* Cl = (unsigned*)Al;  // [128][36] dwords (pad 32->36)
#pragma unroll
    for (int rt = 0; rt < 8; ++rt)
#pragma unroll
      for (int c = 0; c < 2; ++c) {
        int pk = __builtin_amdgcn_cvt_pk_fp8_f32(acc[rt][c][0], acc[rt][c][1], 0, false);
        pk = __builtin_amdgcn_cvt_pk_fp8_f32(acc[rt][c][2], acc[rt][c][3], pk, true);
        Cl[(rt * 16 + l16) * 36 + (w * 2 + c) * 4 + quad] = (unsigned)pk;
      }
    __syncthreads();
#pragma unroll
    for (int i = 0; i < 4; ++i) {
      int c = tid + i * 256;        // 1024 chunks: 128 rows x 8 uint4
      int row = c >> 3, wp = c & 7;
      int m = row0 + row;
      if (m < NN)
        *(uint4*)&feat8u[(size_t)m * 64 + (colbase >> 2) + wp * 4] = *(const uint4*)&Cl[row * 36 + wp * 4];
    }
  } else {
#pragma unroll
    for (int rt = 0; rt < 8; ++rt)
#pragma unroll
      for (int c = 0; c < 2; ++c) {
        int col = (w * 2 + c) * 16 + quad * 4;
        ushort4 o;
        o.x = f2b(acc[rt][c][0]); o.y = f2b(acc[rt][c][1]);
        o.z = f2b(acc[rt][c][2]); o.w = f2b(acc[rt][c][3]);
        *(ushort4*)&Al[(rt * 16 + l16) * 136 + col] = o;
      }
    __syncthreads();
#pragma unroll
    for (int i = 0; i < 8; ++i) {
      int c = tid + i * 256;        // 2048 chunks: 128 rows x 16 uint4
      int row = c >> 4, part = c & 15;
      int m = row0 + row;
      if (m < NN)
        *(uint4*)&resval2[(size_t)m * 256 + colbase + part * 8] = *(const uint4*)&Al[row * 136 + part * 8];
    }
  }
}

// ---------------- res2_f32[N x 64] = relu(A[N x 128] * W_res^T + b_res) (fp32 VALU) ----------------
__global__ __launch_bounds__(256) void k_gemm_nt_bias_relu(const float* __restrict__ A, const float* __restrict__ B,
                                                           const float* __restrict__ bias, float* __restrict__ C) {
  __shared__ float Bl[128][68];
  for (int idx = threadIdx.x; idx < 64 * 128; idx += 256) {
    int d = idx >> 7, k = idx & 127;
    Bl[k][d] = B[d * 128 + k];
  }
  __syncthreads();
  int tx = threadIdx.x & 15, ty = threadIdx.x >> 4;
  int row0 = blockIdx.x * 64 + ty * 4;
  const float* ap[4];
#pragma unroll
  for (int r = 0; r < 4; ++r) ap[r] = A + (size_t)min(row0 + r, NN - 1) * 128;
  float4 acc[4];
#pragma unroll
  for (int r = 0; r < 4; ++r) acc[r] = make_float4(0.f, 0.f, 0.f, 0.f);
#pragma unroll 2
  for (int k0 = 0; k0 < 128; k0 += 4) {
    float4 b0 = *(const float4*)&Bl[k0][tx * 4];
    float4 b1 = *(const float4*)&Bl[k0 + 1][tx * 4];
    float4 b2 = *(const float4*)&Bl[k0 + 2][tx * 4];
    float4 b3 = *(const float4*)&Bl[k0 + 3][tx * 4];
#pragma unroll
    for (int r = 0; r < 4; ++r) {
      float4 a = *(const float4*)(ap[r] + k0);
      fma4(acc[r], a.x, b0); fma4(acc[r], a.y, b1);
      fma4(acc[r], a.z, b2); fma4(acc[r], a.w, b3);
    }
  }
  float4 bv = *(const float4*)&bias[tx * 4];
#pragma unroll
  for (int r = 0; r < 4; ++r) {
    int row = row0 + r;
    if (row < NN) {
      float4 v;
      v.x = fmaxf(acc[r].x + bv.x, 0.f);
      v.y = fmaxf(acc[r].y + bv.y, 0.f);
      v.z = fmaxf(acc[r].z + bv.z, 0.f);
      v.w = fmaxf(acc[r].w + bv.w, 0.f);
      *(float4*)&C[(size_t)row * 64 + tx * 4] = v;
    }
  }
}

// ---------------- fused edge-softmax + aggregation + relu + head-mix conv ----------------
// 4 nodes per wave (degree-sorted via perm, scrambled block order), 16 lanes/node.
// LDS layout [wid][t][g] -> 4 groups read adjacent 16B: conflict-free.
// Inner loop unrolled x2 with both gathers issued before use (MLP=2/wave).
__global__ __launch_bounds__(256) void k_gat(const int* __restrict__ perm, const int* __restrict__ row_start,
                                             const int* __restrict__ deg, const int* __restrict__ csr_src,
                                             const float* __restrict__ el, const float* __restrict__ er,
                                             const unsigned* __restrict__ feat8u,
                                             const unsigned short* __restrict__ resval2,
                                             const float* __restrict__ gat_bias, const float* __restrict__ conv_w,
                                             const float* __restrict__ conv_b, const float* __restrict__ nrm,
                                             float* __restrict__ h0, unsigned short* __restrict__ hs0o) {
  __shared__ int s_src[4][16][4];
  __shared__ float s_x[4][16][4][4];
  int wid = threadIdx.x >> 6, lane = threadIdx.x & 63;
  int g = lane >> 4, k = lane & 15;
  int chunk = (int)(((unsigned)blockIdx.x * SCR) % (unsigned)GP);
  int n = perm[chunk * 16 + wid * 4 + g];
  int s0 = row_start[n], cnt = deg[n];
  float4 er4 = *(const float4*)&er[n * 4];
  unsigned koff = (unsigned)(k << 4);
  f32x2 a01[4], a23[4];
#pragma unroll
  for (int i = 0; i < 4; ++i) { a01[i] = (f32x2){0.f, 0.f}; a23[i] = (f32x2){0.f, 0.f}; }
  f32x2 den01 = (f32x2){0.f, 0.f}, den23 = (f32x2){0.f, 0.f};
  int cm = cnt;
  cm = max(cm, __shfl_xor(cm, 16, 64));
  cm = max(cm, __shfl_xor(cm, 32, 64));
  for (int base = 0; base < cm; base += 16) {
    int j = base + k;
    int s = 0;
    float x0 = 0.f, x1 = 0.f, x2 = 0.f, x3 = 0.f;
    if (j < cnt) {
      s = csr_src[s0 + j];
      float4 el4 = *(const float4*)&el[s * 4];
      float e0 = el4.x + er4.x; e0 = (e0 > 0.f) ? e0 : NEG_SLOPE * e0;
      float e1 = el4.y + er4.y; e1 = (e1 > 0.f) ? e1 : NEG_SLOPE * e1;
      float e2 = el4.z + er4.z; e2 = (e2 > 0.f) ? e2 : NEG_SLOPE * e2;
      float e3 = el4.w + er4.w; e3 = (e3 > 0.f) ? e3 : NEG_SLOPE * e3;
      x0 = __expf(e0); x1 = __expf(e1); x2 = __expf(e2); x3 = __expf(e3);
      den01 += (f32x2){x0, x1}; den23 += (f32x2){x2, x3};
    }
    s_src[wid][k][g] = s;
    *(float4*)&s_x[wid][k][g][0] = make_float4(x0, x1, x2, x3);
    int tm = cm - base; if (tm > 16) tm = 16;
    int tm2 = (tm + 1) & ~1;   // dummy slots have x=0, s=0 -> contribute 0
    for (int t = 0; t < tm2; t += 2) {
      int sa = s_src[wid][t][g];
      int sb = s_src[wid][t + 1][g];
      uint4 fa = *(const uint4*)((const char*)feat8u + (((unsigned)sa << 8) + koff));
      uint4 fb = *(const uint4*)((const char*)feat8u + (((unsigned)sb << 8) + koff));
      float4 xa = *(const float4*)&s_x[wid][t][g][0];
      float4 xb = *(const float4*)&s_x[wid][t + 1][g][0];
      {
        f32x2 x01 = (f32x2){xa.x, xa.y}, x23 = (f32x2){xa.z, xa.w};
        f32x2 lo, hi;
        lo = __builtin_amdgcn_cvt_pk_f32_fp8((int)fa.x, false);
        hi = __builtin_amdgcn_cvt_pk_f32_fp8((int)fa.x, true);
        a01[0] += x01 * lo; a23[0] += x23 * hi;
        lo = __builtin_amdgcn_cvt_pk_f32_fp8((int)fa.y, false);
        hi = __builtin_amdgcn_cvt_pk_f32_fp8((int)fa.y, true);
        a01[1] += x01 * lo; a23[1] += x23 * hi;
        lo = __builtin_amdgcn_cvt_pk_f32_fp8((int)fa.z, false);
        hi = __builtin_amdgcn_cvt_pk_f32_fp8((int)fa.z, true);
        a01[2] += x01 * lo; a23[2] += x23 * hi;
        lo = __builtin_amdgcn_cvt_pk_f32_fp8((int)fa.w, false);
        hi = __builtin_amdgcn_cvt_pk_f32_fp8((int)fa.w, true);
        a01[3] += x01 * lo; a23[3] += x23 * hi;
      }
      {
        f32x2 x01 = (f32x2){xb.x, xb.y}, x23 = (f32x2){xb.z, xb.w};
        f32x2 lo, hi;
        lo = __builtin_amdgcn_cvt_pk_f32_fp8((int)fb.x, false);
        hi = __builtin_amdgcn_cvt_pk_f32_fp8((int)fb.x, true);
        a01[0] += x01 * lo; a23[0] += x23 * hi;
        lo = __builtin_amdgcn_cvt_pk_f32_fp8((int)fb.y, false);
        hi = __builtin_amdgcn_cvt_pk_f32_fp8((int)fb.y, true);
        a01[1] += x01 * lo; a23[1] += x23 * hi;
        lo = __builtin_amdgcn_cvt_pk_f32_fp8((int)fb.z, false);
        hi = __builtin_amdgcn_cvt_pk_f32_fp8((int)fb.z, true);
        a01[2] += x01 * lo; a23[2] += x23 * hi;
        lo = __builtin_amdgcn_cvt_pk_f32_fp8((int)fb.w, false);
        hi = __builtin_amdgcn_cvt_pk_f32_fp8((int)fb.w, true);
        a01[3] += x01 * lo; a23[3] += x23 * hi;
      }
    }
  }
  // den reduce within each 16-lane group
#pragma unroll
  for (int off = 1; off < 16; off <<= 1) {
    den01[0] += __shfl_xor(den01[0], off, 64);
    den01[1] += __shfl_xor(den01[1], off, 64);
    den23[0] += __shfl_xor(den23[0], off, 64);
    den23[1] += __shfl_xor(den23[1], off, 64);
  }
  float i0 = 1.f / fmaxf(den01[0], 1e-9f);
  float i1 = 1.f / fmaxf(den01[1], 1e-9f);
  float i2 = 1.f / fmaxf(den23[0], 1e-9f);
  float i3 = 1.f / fmaxf(den23[1], 1e-9f);
  // epilogue: lane (g,k) handles dims 4k..4k+3 of node n
  uint4 rv0 = *(const uint4*)&resval2[(size_t)n * 256 + (k << 4)];
  uint4 rv1 = *(const uint4*)&resval2[(size_t)n * 256 + (k << 4) + 8];
  unsigned short c[16];
  *(uint4*)&c[0] = rv0; *(uint4*)&c[8] = rv1;
  int d0 = k << 2;
  float4 b0 = *(const float4*)&gat_bias[d0];
  float4 b1 = *(const float4*)&gat_bias[64 + d0];
  float4 b2 = *(const float4*)&gat_bias[128 + d0];
  float4 b3 = *(const float4*)&gat_bias[192 + d0];
  float bh0[4] = {b0.x, b0.y, b0.z, b0.w};
  float bh1[4] = {b1.x, b1.y, b1.z, b1.w};
  float bh2[4] = {b2.x, b2.y, b2.z, b2.w};
  float bh3[4] = {b3.x, b3.y, b3.z, b3.w};
  float cb = conv_b[0];
  float cw0 = conv_w[0], cw1 = conv_w[1], cw2 = conv_w[2], cw3 = conv_w[3];
  float hm[4];
#pragma unroll
  for (int i = 0; i < 4; ++i) {
    float t_, hmv = cb;
    t_ = fmaf(a01[i][0], i0, b2f(c[4 * i + 0]) + bh0[i]); t_ = fmaxf(t_, 0.f); hmv = fmaf(cw0, t_, hmv);
    t_ = fmaf(a01[i][1], i1, b2f(c[4 * i + 1]) + bh1[i]); t_ = fmaxf(t_, 0.f); hmv = fmaf(cw1, t_, hmv);
    t_ = fmaf(a23[i][0], i2, b2f(c[4 * i + 2]) + bh2[i]); t_ = fmaxf(t_, 0.f); hmv = fmaf(cw2, t_, hmv);
    t_ = fmaf(a23[i][1], i3, b2f(c[4 * i + 3]) + bh3[i]); t_ = fmaxf(t_, 0.f); hmv = fmaf(cw3, t_, hmv);
    hm[i] = hmv;
  }
  float nn_ = nrm[n];
  size_t o = (size_t)n * 64 + d0;
  *(float4*)&h0[o] = make_float4(hm[0], hm[1], hm[2], hm[3]);
  ushort4 hs;
  hs.x = f2b(hm[0] * nn_); hs.y = f2b(hm[1] * nn_);
  hs.z = f2b(hm[2] * nn_); hs.w = f2b(hm[3] * nn_);
  *(ushort4*)&hs0o[o] = hs;
}

// ---------------- APPNP gather core: 4 nodes/wave, 16 lanes/node, lane owns dims 4k..4k+3 ----------------
// Unrolled x4: 4 gathers in flight per wave iteration; tails read zero row NN.
__device__ __forceinline__ void gather4(const int* __restrict__ perm, const int* __restrict__ row_start,
                                        const int* __restrict__ deg, const int* __restrict__ csr_src,
                                        const unsigned short* __restrict__ hs_in,
                                        int wid, int lane, int& n, int& k, float (&a)[4]) {
  __shared__ int s_src[4][16][4];
  int g = lane >> 4; k = lane & 15;
  int chunk = (int)(((unsigned)blockIdx.x * SCR) % (unsigned)GP);
  n = perm[chunk * 16 + wid * 4 + g];
  int s0 = row_start[n], cnt = deg[n];
  unsigned koff = (unsigned)(k << 3);
  a[0] = 0.f; a[1] = 0.f; a[2] = 0.f; a[3] = 0.f;
  int cm = cnt;
  cm = max(cm, __shfl_xor(cm, 16, 64));
  cm = max(cm, __shfl_xor(cm, 32, 64));
  for (int base = 0; base < cm; base += 16) {
    int j = base + k;
    s_src[wid][k][g] = (j < cnt) ? csr_src[s0 + j] : NN;  // row NN is zeroed
    int tm = cm - base; if (tm > 16) tm = 16;
    int tm4 = (tm + 3) & ~3;   // dummy slots read the zero row
    for (int t = 0; t < tm4; t += 4) {
      int sa = s_src[wid][t][g];
      int sb = s_src[wid][t + 1][g];
      int sc2 = s_src[wid][t + 2][g];
      int sd = s_src[wid][t + 3][g];
      uint2 ua = *(const uint2*)((const char*)hs_in + (((unsigned)sa << 7) + koff));
      uint2 ub = *(const uint2*)((const char*)hs_in + (((unsigned)sb << 7) + koff));
      uint2 uc = *(const uint2*)((const char*)hs_in + (((unsigned)sc2 << 7) + koff));
      uint2 ud = *(const uint2*)((const char*)hs_in + (((unsigned)sd << 7) + koff));
      a[0] += __uint_as_float(ua.x << 16) + __uint_as_float(ub.x << 16);
      a[1] += __uint_as_float(ua.x & 0xFFFF0000u) + __uint_as_float(ub.x & 0xFFFF0000u);
      a[2] += __uint_as_float(ua.y << 16) + __uint_as_float(ub.y << 16);
      a[3] += __uint_as_float(ua.y & 0xFFFF0000u) + __uint_as_float(ub.y & 0xFFFF0000u);
      a[0] += __uint_as_float(uc.x << 16) + __uint_as_float(ud.x << 16);
      a[1] += __uint_as_float(uc.x & 0xFFFF0000u) + __uint_as_float(ud.x & 0xFFFF0000u);
      a[2] += __uint_as_float(uc.y << 16) + __uint_as_float(ud.y << 16);
      a[3] += __uint_as_float(uc.y & 0xFFFF0000u) + __uint_as_float(ud.y & 0xFFFF0000u);
    }
  }
}

// ---------------- APPNP step (mid): hs_out = bf16(0.5*nrm^2*acc + 0.5*hs0) ----------------
__global__ __launch_bounds__(256) void k_gather_mid(const int* __restrict__ perm, const int* __restrict__ row_start,
                                                    const int* __restrict__ deg, const int* __restrict__ csr_src,
                                                    const unsigned short* __restrict__ hs_in,
                                                    const float* __restrict__ nrm,
                                                    const unsigned short* __restrict__ hs0,
                                                    unsigned short* __restrict__ hs_out) {
  int wid = threadIdx.x >> 6, lane = threadIdx.x & 63;
  int n, k; float a[4];
  gather4(perm, row_start, deg, csr_src, hs_in, wid, lane, n, k, a);
  size_t o = (size_t)n * 64 + (k << 2);
  float nn_ = nrm[n];
  float hnn = 0.5f * nn_ * nn_;
  uint2 z = *(const uint2*)&hs0[o];
  ushort4 ov;
  ov.x = f2b(fmaf(hnn, a[0], 0.5f * __uint_as_float(z.x << 16)));
  ov.y = f2b(fmaf(hnn, a[1], 0.5f * __uint_as_float(z.x & 0xFFFF0000u)));
  ov.z = f2b(fmaf(hnn, a[2], 0.5f * __uint_as_float(z.y << 16)));
  ov.w = f2b(fmaf(hnn, a[3], 0.5f * __uint_as_float(z.y & 0xFFFF0000u)));
  *(ushort4*)&hs_out[o] = ov;
}

// ---------------- APPNP step (last) fused with final residual add: h0io = appnp + res2 (f32) ----------------
__global__ __launch_bounds__(256) void k_gather_last(const int* __restrict__ perm, const int* __restrict__ row_start,
                                                     const int* __restrict__ deg, const int* __restrict__ csr_src,
                                                     const unsigned short* __restrict__ hs_in,
                                                     const float* __restrict__ nrm,
                                                     const float* __restrict__ res2,
                                                     float* h0io) {
  int wid = threadIdx.x >> 6, lane = threadIdx.x & 63;
  int n, k; float a[4];
  gather4(perm, row_start, deg, csr_src, hs_in, wid, lane, n, k, a);
  size_t o = (size_t)n * 64 + (k << 2);
  float nn_ = nrm[n];
  float hn = 0.5f * nn_;
  float4 h4 = *(const float4*)&h0io[o];
  float4 r4 = *(const float4*)&res2[o];
  float4 v;
  v.x = fmaf(hn, a[0], 0.5f * h4.x) + r4.x;
  v.y = fmaf(hn, a[1], 0.5f * h4.y) + r4.y;
  v.z = fmaf(hn, a[2], 0.5f * h4.z) + r4.z;
  v.w = fmaf(hn, a[3], 0.5f * h4.w) + r4.w;
  *(float4*)&h0io[o] = v;
}

// ---------------- BN partial sums (pure reduction over hfin f32) ----------------
__global__ __launch_bounds__(256) void k_finred(const float* __restrict__ hfin, float* __restrict__ bn) {
  __shared__ float s1[256], s2[256];
  int d = threadIdx.x & 63;
  int rb = blockIdx.x * 64;
  float sum = 0.f, sq = 0.f;
  for (int r = threadIdx.x >> 6; r < 64; r += 4) {
    int n = rb + r;
    if (n < NN) {
      float v = hfin[(size_t)n * 64 + d];
      sum += v; sq += v * v;
    }
  }
  s1[threadIdx.x] = sum; s2[threadIdx.x] = sq;
  __syncthreads();
  if (threadIdx.x < 128) { s1[threadIdx.x] += s1[threadIdx.x + 128]; s2[threadIdx.x] += s2[threadIdx.x + 128]; }
  __syncthreads();
  if (threadIdx.x < 64) {
    atomicAdd(&bn[d], s1[threadIdx.x] + s1[threadIdx.x + 64]);
    atomicAdd(&bn[64 + d], s2[threadIdx.x] + s2[threadIdx.x + 64]);
  }
}

__global__ void k_bnstats(const float* __restrict__ bn, const float* __restrict__ gamma,
                          const float* __restrict__ beta, float* __restrict__ bns) {
  int d = threadIdx.x;
  float mu = bn[d] * (1.0f / NN);
  float var = fmaxf(bn[64 + d] * (1.0f / NN) - mu * mu, 0.f);
  float sc = rsqrtf(var + 1e-5f) * gamma[d];
  bns[d] = sc;
  bns[64 + d] = beta[d] - mu * sc;
}

__global__ __launch_bounds__(256) void k_bnapply(const float* __restrict__ h, const float* __restrict__ bns,
                                                 float* __restrict__ out) {
  int i = blockIdx.x * 256 + threadIdx.x;
  if (i < NN * 64) {
    int d = i & 63;
    out[i] = fmaf(h[i], bns[d], bns[64 + d]);
  }
}

extern "C" void kernel_launch(void* const* d_in, const int* in_sizes, int n_in,
                              void* d_out, int out_size, void* d_ws, size_t ws_size,
                              hipStream_t stream) {
  const float* node_feats = (const float*)d_in[0];
  const int* src = (const int*)d_in[1];
  const int* dst = (const int*)d_in[2];
  const float* W_fc = (const float*)d_in[3];
  const float* attn_l = (const float*)d_in[4];
  const float* attn_r = (const float*)d_in[5];
  const float* W_res_gat = (const float*)d_in[6];
  const float* gat_bias = (const float*)d_in[7];
  const float* conv_w = (const float*)d_in[8];
  const float* conv_b = (const float*)d_in[9];
  const float* W_res = (const float*)d_in[10];
  const float* b_res = (const float*)d_in[11];
  const float* gamma = (const float*)d_in[12];
  const float* beta = (const float*)d_in[13];
  float* out = (float*)d_out;

  char* base = (char*)d_ws;
  size_t off = 0;
  auto alloc = [&](size_t bytes) -> char* {
    char* p = base + off;
    off = (off + bytes + 255) & ~(size_t)255;
    return p;
  };
  unsigned* feat8u        = (unsigned*)alloc((size_t)NN * 256);                  // 25.6 MB fp8 (n,d,h)
  unsigned short* resval2 = (unsigned short*)alloc((size_t)NN * 256 * 2);        // 51.2 MB bf16; res2 f32 aliases after k_gat
  float* res2             = (float*)resval2;
  float* el               = (float*)alloc((size_t)NN * 4 * 4);
  float* er               = (float*)alloc((size_t)NN * 4 * 4);
  float* h0               = (float*)alloc((size_t)NN * 64 * 4);                  // 25.6 MB; Abf aliases BEFORE k_gat; hfin at end
  unsigned short* Abf     = (unsigned short*)h0;
  unsigned short* hs0     = (unsigned short*)alloc((size_t)(NN + 1) * 64 * 2);   // 12.8 MB bf16(h0*nrm) + dummy row
  unsigned short* hsA     = (unsigned short*)alloc((size_t)(NN + 1) * 64 * 2);
  unsigned short* hsB     = (unsigned short*)alloc((size_t)(NN + 1) * 64 * 2);
  int* csr_src            = (int*)alloc((size_t)NE * 4);
  float* nrm              = (float*)alloc((size_t)NN * 4);
  int* row_start          = (int*)alloc((size_t)NN * 4);
  int* perm               = (int*)alloc((size_t)NN * 4);
  int* bcount             = (int*)alloc((size_t)GB * 64 * 4);
  int* bsum               = (int*)alloc((size_t)GB * 4);
  int* bbase              = (int*)alloc((size_t)GB * 4);
  int* dbase              = (int*)alloc(64 * 4);
  unsigned short* Bpacked = (unsigned short*)alloc((size_t)4 * 16384 * 2);
  float* w_elr            = (float*)alloc((size_t)8 * 128 * 4);
  size_t zoff = off;
  int* deg                = (int*)alloc((size_t)NN * 4);
  int* cursor             = (int*)alloc((size_t)NN * 4);
  float* bn               = (float*)alloc(256 * 4);
  float* hfin             = h0;

  int zwords = (int)((off - zoff) / 4);
  int gE = (NE + 255) / 256;
  int gM = (NN + 63) / 64;
  int gV = (NN * 64 + 255) / 256;

  k_zero<<<(zwords + 255) / 256, 256, 0, stream>>>((int*)(base + zoff), zwords);
  k_zrow<<<1, 64, 0, stream>>>(hs0, hsA, hsB);
  k_deg<<<gE, 256, 0, stream>>>(dst, deg);
  k_hist<<<GB, 256, 0, stream>>>(deg, bcount, bsum);
  k_scan<<<1, 64, 0, stream>>>(bcount, bsum, dbase, bbase);
  k_rows<<<GB, 256, 0, stream>>>(deg, bcount, dbase, bbase, row_start, nrm, perm);
  k_scatter<<<gE, 256, 0, stream>>>(src, dst, row_start, cursor, csr_src);

  k_cast<<<(NN * 128 / 4 + 255) / 256, 256, 0, stream>>>(node_feats, Abf);
  k_prepB<<<dim3(8, 4), 256, 0, stream>>>(W_fc, W_res_gat, Bpacked);
  k_prepw<<<4, 256, 0, stream>>>(W_fc, attn_l, attn_r, w_elr);
  k_gemm_mfma<<<dim3((NN + 127) / 128, 4), 256, 0, stream>>>(Abf, Bpacked, feat8u, resval2);

  k_elr2<<<(NN + 31) / 32, 256, 0, stream>>>(Abf, w_elr, el, er);
  k_gat<<<GP, 256, 0, stream>>>(perm, row_start, deg, csr_src, el, er, feat8u, resval2,
                                gat_bias, conv_w, conv_b, nrm, h0, hs0);

  // resval2 dead now; res2 (f32) reuses its space
  k_gemm_nt_bias_relu<<<gM, 256, 0, stream>>>(node_feats, W_res, b_res, res2);

  k_gather_mid<<<GP, 256, 0, stream>>>(perm, row_start, deg, csr_src, hs0, nrm, hs0, hsA);
  k_gather_mid<<<GP, 256, 0, stream>>>(perm, row_start, deg, csr_src, hsA, nrm, hs0, hsB);
  k_gather_mid<<<GP, 256, 0, stream>>>(perm, row_start, deg, csr_src, hsB, nrm, hs0, hsA);
  k_gather_mid<<<GP, 256, 0, stream>>>(perm, row_start, deg, csr_src, hsA, nrm, hs0, hsB);
  // last step fused with residual add: writes hfin (= h0) in f32
  k_gather_last<<<GP, 256, 0, stream>>>(perm, row_start, deg, csr_src, hsB, nrm, res2, hfin);

  k_finred<<<gM, 256, 0, stream>>>(hfin, bn);
  k_bnstats<<<1, 64, 0, stream>>>(bn, gamma, beta, bn + 128);
  k_bnapply<<<gV, 256, 0, stream>>>(hfin, bn + 128, out);
}